// Round 1
// 178.851 us; speedup vs baseline: 1.0081x; 1.0081x over previous
//
#include <hip/hip_runtime.h>
#include <hip/hip_bf16.h>

// GPT-2 attention block. Inputs/outputs fp32; internal bf16 MFMA, fp32 accum.
// B=4, S=1024, D=1024, H=16, hd=64.
//
// R13: gemm_qkv rewritten as 256x256 8-phase counted-vmcnt template
//      (T2 xor-swizzle + T3/T4 8-phase + T5 setprio, 512 thr, 128KB LDS,
//      192 blocks w/ XCD swizzle). gemm_out keeps the R8 128x128 core
//      (256-block grid fills all CUs there). prep/transpose_v/attn verbatim.

typedef __bf16 bf16x8 __attribute__((ext_vector_type(8)));
typedef float f32x4 __attribute__((ext_vector_type(4)));

__device__ __forceinline__ void load_lds16(const void* g, void* l) {
  __builtin_amdgcn_global_load_lds(
      (const __attribute__((address_space(1))) void*)g,
      (__attribute__((address_space(3))) void*)l, 16, 0, 0);
}

// ---------------- fused prep: transpose w_attn, w_proj; convert x ----------------
__global__ __launch_bounds__(256) void prep(
    const float* __restrict__ x, const float* __restrict__ w_attn,
    const float* __restrict__ w_proj, __bf16* __restrict__ Xb,
    __bf16* __restrict__ WT_attn, __bf16* __restrict__ WT_proj) {
  __shared__ __bf16 tile[32][33];
  const int blk = blockIdx.x;
  const int tid = threadIdx.x;
  if (blk < 4096) {  // transpose (block-uniform branch)
    const float* W;
    __bf16* WT;
    int n0, k0, N;
    if (blk < 3072) {
      W = w_attn; WT = WT_attn; N = 3072;
      n0 = (blk % 96) * 32; k0 = (blk / 96) * 32;
    } else {
      W = w_proj; WT = WT_proj; N = 1024;
      const int t = blk - 3072;
      n0 = (t & 31) * 32; k0 = (t >> 5) * 32;
    }
    const int tx = tid & 31, ty = tid >> 5;
#pragma unroll
    for (int j = 0; j < 32; j += 8)
      tile[ty + j][tx] = (__bf16)W[(size_t)(k0 + ty + j) * N + n0 + tx];
    __syncthreads();
#pragma unroll
    for (int j = 0; j < 32; j += 8)
      WT[(size_t)(n0 + ty + j) * 1024 + k0 + tx] = tile[tx][ty + j];
  } else {  // x -> bf16, 16 elems/thread
    const size_t i = (size_t)(blk - 4096) * 4096 + tid * 16;
    const float4* xp = (const float4*)(x + i);
    float4 a = xp[0], b = xp[1], c = xp[2], d = xp[3];
    bf16x8 o0, o1;
    o0[0] = (__bf16)a.x; o0[1] = (__bf16)a.y; o0[2] = (__bf16)a.z; o0[3] = (__bf16)a.w;
    o0[4] = (__bf16)b.x; o0[5] = (__bf16)b.y; o0[6] = (__bf16)b.z; o0[7] = (__bf16)b.w;
    o1[0] = (__bf16)c.x; o1[1] = (__bf16)c.y; o1[2] = (__bf16)c.z; o1[3] = (__bf16)c.w;
    o1[4] = (__bf16)d.x; o1[5] = (__bf16)d.y; o1[6] = (__bf16)d.z; o1[7] = (__bf16)d.w;
    *(bf16x8*)(Xb + i) = o0;
    *(bf16x8*)(Xb + i + 8) = o1;
  }
}

// ---------------- V transpose: VT[bh][d][s] from Vr[s_global][1024] ----------------
__global__ __launch_bounds__(256) void transpose_v(
    const __bf16* __restrict__ Vr, __bf16* __restrict__ VT) {
  const int lane = threadIdx.x & 63, wave = threadIdx.x >> 6;
  const int bh = blockIdx.x >> 4;
  const int kb = (blockIdx.x & 15) * 64;
  const int b = bh >> 4, h = bh & 15;
  const __bf16* src =
      Vr + (size_t)(b * 1024 + kb + lane) * 1024 + h * 64 + wave * 16;
  bf16x8 v0 = *(const bf16x8*)src;
  bf16x8 v1 = *(const bf16x8*)(src + 8);
  __bf16* dst = VT + ((size_t)bh * 64 + wave * 16) * 1024 + kb + lane;
#pragma unroll
  for (int i = 0; i < 8; ++i) {
    dst[(size_t)i * 1024] = v0[i];
    dst[(size_t)(i + 8) * 1024] = v1[i];
  }
}

// ================= GEMM core (R8: BK=32, 16 KB LDS) — used by gemm_out =========
#define GEMM_CORE(A_, BT_, K_)                                                   \
  __shared__ __bf16 sA[128 * 32];                                               \
  __shared__ __bf16 sB[128 * 32];                                               \
  const int tid = threadIdx.x;                                                  \
  const int lane = tid & 63;                                                    \
  const int wave = tid >> 6;                                                    \
  const int waveM = wave >> 1, waveN = wave & 1;                                \
  const int quad = lane >> 4;                                                   \
  const int l16 = lane & 15;                                                    \
  const int rowBase = blockIdx.y * 128;                                         \
  const int colBase = blockIdx.x * 128;                                         \
  const int rIn = lane >> 2;                                                    \
  const int sIn = lane & 3;                                                     \
  const int gc = sIn ^ (rIn & 3) ^ ((rIn >> 2) & 3);                            \
  const int readSlot = quad ^ (l16 & 3) ^ ((l16 >> 2) & 3);                     \
  f32x4 acc[4][4] = {};                                                         \
  for (int k0 = 0; k0 < K_; k0 += 32) {                                         \
    __syncthreads();                                                            \
    _Pragma("unroll") for (int j = 0; j < 2; ++j) {                             \
      const int rb = wave * 32 + j * 16;                                        \
      load_lds16(&A_[(size_t)(rowBase + rb + rIn) * K_ + k0 + gc * 8],          \
                 &sA[rb * 32]);                                                 \
      load_lds16(&BT_[(size_t)(colBase + rb + rIn) * K_ + k0 + gc * 8],         \
                 &sB[rb * 32]);                                                 \
    }                                                                           \
    __syncthreads();                                                            \
    bf16x8 af[4], bfr[4];                                                       \
    _Pragma("unroll") for (int mt = 0; mt < 4; ++mt)                            \
      af[mt] = *(const bf16x8*)(&sA[(waveM * 64 + mt * 16 + l16) * 32 +         \
                                    readSlot * 8]);                             \
    _Pragma("unroll") for (int nt = 0; nt < 4; ++nt)                            \
      bfr[nt] = *(const bf16x8*)(&sB[(waveN * 64 + nt * 16 + l16) * 32 +        \
                                     readSlot * 8]);                            \
    _Pragma("unroll") for (int mt = 0; mt < 4; ++mt)                            \
    _Pragma("unroll") for (int nt = 0; nt < 4; ++nt)                            \
      acc[mt][nt] = __builtin_amdgcn_mfma_f32_16x16x32_bf16(                    \
          af[mt], bfr[nt], acc[mt][nt], 0, 0, 0);                               \
  }

// ================= GEMM1: 256x256 8-phase template (QKV) =================
// 512 threads = 8 waves (2M x 4N). BK=64, double-buffered 128 KB LDS.
// LDS map (bf16 elems): buf b at b*32768; A halves at +0,+8192; B at +16384,+24576.
// Swizzle: slot s of row r holds k-chunk c = s ^ (r&7) (16B chunks).
// Stage schedule per iter t (tiles E=2t in buf0, O=2t+1 in buf1):
//   ph1: O.A1 | ph3: (E+2).B0 | ph4: (E+2).B1,(E+2).A0 + vmcnt(6)
//   ph5: (E+2).A1 | ph7: (O+2).B0 | ph8: (O+2).B1,(O+2).A0 + vmcnt(6)
// vmcnt(6) at ph4 lands everything through this iter's ph1 (all of O);
// vmcnt(6) at ph8 lands through ph5 (all of E+2). Each half is re-staged
// only in a phase strictly after its last reader's lgkmcnt(0).

#define BAR8 asm volatile("s_barrier" ::: "memory")
#define LGKM0 asm volatile("s_waitcnt lgkmcnt(0)" ::: "memory")

#define STG(GMAT, GROW0, K0, LOFF)                                             \
  _Pragma("unroll") for (int i_ = 0; i_ < 2; ++i_)                             \
    load_lds16((GMAT) + (size_t)((GROW0) + i_ * 64 + wave * 8 + srow) * 1024 + \
                   (K0) + schunk * 8,                                          \
               smem8 + (LOFF) + (i_ * 64 + wave * 8) * 64);

#define LDA8(BASE, MH)                                                         \
  _Pragma("unroll") for (int m_ = 0; m_ < 4; ++m_)                             \
  _Pragma("unroll") for (int kk_ = 0; kk_ < 2; ++kk_)                          \
    af[m_][kk_] = *(const bf16x8*)((BASE) + ((MH)*64 + m_ * 16 + l16) * 64 +   \
                                   (((kk_ * 4 + quad) ^ rsw) * 8));

#define LDB8(BASE, NLO)                                                        \
  _Pragma("unroll") for (int n_ = 0; n_ < 2; ++n_)                             \
  _Pragma("unroll") for (int kk_ = 0; kk_ < 2; ++kk_)                          \
    bf[(NLO) + n_][kk_] =                                                      \
        *(const bf16x8*)((BASE) + ((waveN & 1) * 64 + ((NLO) + n_) * 16 +      \
                                   l16) * 64 +                                 \
                         (((kk_ * 4 + quad) ^ rsw) * 8));

#define MFMA_HALF(MH, NLO)                                                     \
  __builtin_amdgcn_s_setprio(1);                                               \
  _Pragma("unroll") for (int m_ = 0; m_ < 4; ++m_)                             \
  _Pragma("unroll") for (int n_ = 0; n_ < 2; ++n_) {                           \
    acc[(MH)*4 + m_][(NLO) + n_] = __builtin_amdgcn_mfma_f32_16x16x32_bf16(    \
        af[m_][0], bf[(NLO) + n_][0], acc[(MH)*4 + m_][(NLO) + n_], 0, 0, 0);  \
    acc[(MH)*4 + m_][(NLO) + n_] = __builtin_amdgcn_mfma_f32_16x16x32_bf16(    \
        af[m_][1], bf[(NLO) + n_][1], acc[(MH)*4 + m_][(NLO) + n_], 0, 0, 0);  \
  }                                                                            \
  __builtin_amdgcn_s_setprio(0);

__global__ __launch_bounds__(512, 2) void gemm_qkv8(
    const __bf16* __restrict__ A, const __bf16* __restrict__ BT,
    const float* __restrict__ bias, __bf16* __restrict__ Qp,
    __bf16* __restrict__ Kp, __bf16* __restrict__ Vr) {
  __shared__ __bf16 smem8[65536];  // 128 KB
  const int tid = threadIdx.x;
  const int lane = tid & 63;
  const int wave = tid >> 6;
  const int waveM = wave >> 2;  // 0..1
  const int waveN = wave & 3;   // 0..3
  const int l16 = lane & 15;
  const int quad = lane >> 4;
  const int rsw = l16 & 7;
  const int srow = lane >> 3;            // staging row-in-8
  const int schunk = (lane & 7) ^ srow;  // pre-swizzled source chunk

  // XCD-aware bijective swizzle: 192 blocks = 8 XCDs x 24
  const int bid = blockIdx.x;
  const int swz = (bid & 7) * 24 + (bid >> 3);
  const int tm = swz / 12, tn = swz - (swz / 12) * 12;
  const int rowBase = tm * 256;
  const int colBase = tn * 256;

  const __bf16* aRd = smem8 + waveM * 8192;                 // buf0 A (own half)
  const __bf16* bRd = smem8 + 16384 + (waveN >> 1) * 8192;  // buf0 B (own half)

  f32x4 acc[8][4] = {};
  bf16x8 af[4][2], bf[4][2];

  // ---- prologue: stage T0 fully, T1 {B0,B1,A0}
  STG(A, rowBase, 0, 0);
  STG(A, rowBase + 128, 0, 8192);
  STG(BT, colBase, 0, 16384);
  STG(BT, colBase + 128, 0, 24576);
  STG(BT, colBase, 64, 32768 + 16384);
  STG(BT, colBase + 128, 64, 32768 + 24576);
  STG(A, rowBase, 64, 32768);
  asm volatile("s_waitcnt vmcnt(6)" ::: "memory");  // T0 landed
  BAR8;

  for (int t = 0; t < 8; ++t) {
    const int kO = t * 128 + 64;   // odd tile K offset (for O.A1 stage)
    const int kS2 = t * 128 + 128; // prefetch tile for buf0
    const int kS3 = t * 128 + 192; // prefetch tile for buf1
    const bool s2 = kS2 < 1024;
    const bool s3 = kS3 < 1024;

    // ---- phase 1: read E.A-mh0 + E.B-n01 ; stage O.A1
    LDA8(aRd, 0);
    LDB8(bRd, 0);
    STG(A, rowBase + 128, kO, 32768 + 8192);
    BAR8; LGKM0;
    MFMA_HALF(0, 0);
    BAR8;

    // ---- phase 2: read E.B-n23
    LDB8(bRd, 2);
    BAR8; LGKM0;
    MFMA_HALF(0, 2);
    BAR8;

    // ---- phase 3: read E.A-mh1 ; stage (E+2).B0
    LDA8(aRd, 1);
    if (s2) { STG(BT, colBase, kS2, 16384); }
    BAR8; LGKM0;
    MFMA_HALF(1, 2);
    BAR8;

    // ---- phase 4: stage (E+2).B1 + (E+2).A0 ; counted vmcnt
    if (s2) {
      STG(BT, colBase + 128, kS2, 24576);
      STG(A, rowBase, kS2, 0);
      asm volatile("s_waitcnt vmcnt(6)" ::: "memory");  // all of O landed
    } else {
      asm volatile("s_waitcnt vmcnt(0)" ::: "memory");  // last iter: drain
    }
    BAR8;
    MFMA_HALF(1, 0);
    BAR8;

    // ---- phase 5: read O.A-mh0 + O.B-n01 ; stage (E+2).A1
    LDA8(aRd + 32768, 0);
    LDB8(bRd + 32768, 0);
    if (s2) { STG(A, rowBase + 128, kS2, 8192); }
    BAR8; LGKM0;
    MFMA_HALF(0, 0);
    BAR8;

    // ---- phase 6: read O.B-n23
    LDB8(bRd + 32768, 2);
    BAR8; LGKM0;
    MFMA_HALF(0, 2);
    BAR8;

    // ---- phase 7: read O.A-mh1 ; stage (O+2).B0
    LDA8(aRd + 32768, 1);
    if (s3) { STG(BT, colBase, kS3, 32768 + 16384); }
    BAR8; LGKM0;
    MFMA_HALF(1, 2);
    BAR8;

    // ---- phase 8: stage (O+2).B1 + (O+2).A0 ; counted vmcnt
    if (s3) {
      STG(BT, colBase + 128, kS3, 32768 + 24576);
      STG(A, rowBase, kS3, 32768);
    }
    asm volatile("s_waitcnt vmcnt(6)" ::: "memory");  // all of E+2 landed
    BAR8;
    MFMA_HALF(1, 0);
    BAR8;
  }

  // ---- epilogue: packed Qp/Kp, row-major Vr
  const int seg = colBase >> 10;  // 0=Q 1=K 2=V (block-uniform)
#pragma unroll
  for (int mm = 0; mm < 8; ++mm) {
    const int row0 = rowBase + waveM * 128 + mm * 16 + quad * 4;
#pragma unroll
    for (int n = 0; n < 4; ++n) {
      const int col = colBase + waveN * 64 + n * 16 + l16;
      const float bv = bias[col];
      const int cc = col & 1023;
#pragma unroll
      for (int r = 0; r < 4; ++r) {
        const int row = row0 + r;
        const float v = acc[mm][n][r] + bv;
        if (seg == 2) {
          Vr[(size_t)row * 1024 + cc] = (__bf16)v;
        } else {
          const int bh = ((row >> 10) << 4) + (cc >> 6);
          __bf16* dst = (seg == 0) ? Qp : Kp;
          dst[((size_t)bh << 16) + (size_t)(row & 1023) * 64 + (cc & 63)] =
              (__bf16)v;
        }
      }
    }
  }
}

// ---------------- GEMM2: out = A @ WT^T + bias (fp32 out) ----------------
__global__ __launch_bounds__(256) void gemm_out(
    const __bf16* __restrict__ A, const __bf16* __restrict__ BT,
    const float* __restrict__ bias, float* __restrict__ C) {
  GEMM_CORE(A, BT, 1024)
#pragma unroll
  for (int mt = 0; mt < 4; ++mt) {
    const int row = rowBase + waveM * 64 + mt * 16 + quad * 4;
#pragma unroll
    for (int nt = 0; nt < 4; ++nt) {
      const int col = colBase + waveN * 64 + nt * 16 + l16;
      const float bv = bias[col];
#pragma unroll
      for (int r = 0; r < 4; ++r)
        C[(size_t)(row + r) * 1024 + col] = acc[mt][nt][r] + bv;
    }
  }
}

// ---------------- paired flash attention (R9 kernel, verbatim) ----------------
__global__ __launch_bounds__(256) void attn_mfma(
    const __bf16* __restrict__ Qp, const __bf16* __restrict__ Kp,
    const __bf16* __restrict__ VT, __bf16* __restrict__ Aout) {
  __shared__ __bf16 sK[128 * 64];      // 16 KB, swizzled packed K lines
  __shared__ __bf16 sV[64 * 128];      // 16 KB, swizzled V^T
  __shared__ __bf16 sP[4 * 16 * 128];  // 16 KB, per-wave P regions

  const int tid = threadIdx.x;
  const int lane = tid & 63;
  const int wave = tid >> 6;
  const int quad = lane >> 4;
  const int l16 = lane & 15;
  const int swq = l16 & 7;

  const int bh = blockIdx.x >> 3;
  const int pr = blockIdx.x & 7;
  const int b = bh >> 4, h = bh & 15;
  const int qbA = pr * 64, qbB = (15 - pr) * 64;
  const int ktA_max = pr >> 1, ktB_max = (15 - pr) >> 1;

  const __bf16* Qb = Qp + ((size_t)bh << 16);
  const __bf16* Kb = Kp + ((size_t)bh << 16);
  const __bf16* VTb = VT + (size_t)bh * 64 * 1024;

  bf16x8 qA0A, qA1A, qA0B, qA1B;
  {
    const __bf16* qr = Qb + (size_t)(qbA + wave * 16 + l16) * 64 + quad * 8;
    qA0A = *(const bf16x8*)qr;
    qA1A = *(const bf16x8*)(qr + 32);
    qr = Qb + (size_t)(qbB + wave * 16 + l16) * 64 + quad * 8;
    qA0B = *(const bf16x8*)qr;
    qA1B = *(const bf16x8*)(qr + 32);
  }

  f32x4 OA[4] = {}, OB[4] = {};
  float psA[4] = {0.f, 0.f, 0.f, 0.f}, psB[4] = {0.f, 0.f, 0.f, 0.f};
  __bf16* pw = sP + wave * 2048;

  for (int kt = 0; kt <= ktB_max; ++kt) {
    const int kb = kt * 128;
    __syncthreads();  // prior iter's sK/sV reads complete

    // ---- DMA stage K: sK[key][slot s] = line chunk s^(key&7)
#pragma unroll
    for (int i = 0; i < 4; ++i) {
      const int rb = wave * 32 + i * 8;
      load_lds16(Kb + (size_t)(kb + rb + (lane >> 3)) * 64 +
                     (((lane & 7) ^ ((lane >> 3) & 7)) << 3),
                 &sK[rb * 64]);
    }
    // ---- DMA stage V^T: sV[d][slot s] = key-chunk s^(d&7)
#pragma unroll
    for (int i = 0; i < 4; ++i) {
      const int db = wave * 16 + i * 4;
      const int d = db + (lane >> 4);
      load_lds16(VTb + (size_t)d * 1024 + kb + (((lane & 15) ^ (d & 7)) << 3),
                 &sV[db * 128]);
    }
    __syncthreads();  // staged

    // ================= q-tile B (always active) =================
    {
      float sc[8][4];
#pragma unroll
      for (int n = 0; n < 8; ++n) {
        const int key = n * 16 + l16;
        bf16x8 kB0 = *(const bf16x8*)(&sK[key * 64 + ((quad ^ swq) << 3)]);
        bf16x8 kB1 = *(const bf16x8*)(&sK[key * 64 + (((quad + 4) ^ swq) << 3)]);
        f32x4 c = {};
        c = __builtin_amdgcn_mfma_f32_16x16x32_bf16(qA0B, kB0, c, 0, 0, 0);
        c = __builtin_amdgcn_mfma_f32_16x16x32_bf16(qA1B, kB1, c, 0, 0, 0);
#pragma unroll
        for (int r = 0; r < 4; ++r) sc[n][r] = c[r] * 0.125f;
      }
      if (kt == ktB_max) {
#pragma unroll
        for (int n = 0; n < 8; ++n) {
          const int kg = kb + n * 16 + l16;
#pragma unroll
          for (int r = 0; r < 4; ++r)
            if (kg > qbB + wave * 16 + quad * 4 + r) sc[n][r] = -1.0e30f;
        }
      }
#pragma unroll
      for (int n = 0; n < 8; ++n)
#pragma unroll
        for (int r = 0; r < 4; ++r) {
          float p = __expf(fminf(sc[n][r], 60.0f));
          sc[n][r] = p;
          psB[r] += p;
        }
      {
        const int kb8 = l16 >> 3, lo = l16 & 7;
#pragma unroll
        for (int n = 0; n < 8; ++n) {
          const int chunk = n * 2 + kb8;
#pragma unroll
          for (int r = 0; r < 4; ++r) {
            const int q = quad * 4 + r;
            pw[q * 128 + ((chunk ^ (q & 7)) << 3) + lo] = (__bf16)sc[n][r];
          }
        }
      }
#pragma unroll
      for (int cc = 0; cc < 4; ++cc) {
        bf16x8 pA = *(const bf16x8*)(&pw[l16 * 128 + (((cc * 4 + quad) ^ swq) << 3)]);
#pragma unroll
        for (int nt = 0; nt < 4; ++nt) {
          bf16x8 vB = *(const bf16x8*)(&sV[(nt * 16 + l16) * 128 +
                                           (((cc * 4 + quad) ^ swq) << 3)]);
          OB[nt] = __builtin_amdgcn_mfma_f32_16x16x32_bf16(pA, vB, OB[nt], 0, 0, 0);
        }
      }
    }

    // ================= q-tile A (active while kt <= ktA_max) =================
    if (kt <= ktA_max) {
      float sc[8][4];
#pragma unroll
      for (int n = 0; n < 8; ++n) {
        const int key = n * 16 + l16;
        bf16x8 kB0 = *(const bf16x8*)(&sK[key * 64 + ((quad ^ swq) << 3)]);
        bf16x8 kB1 = *(const bf16x8*)(&sK[key * 64 + (((quad + 4) ^ swq) << 3)]);
        f32x4 c = {};
        c = __builtin_amdgcn_mfma_f32_16x16x32_bf16(qA0A, kB0, c, 0, 0, 0);
        c = __builtin_amdgcn_mfma_f32_16x16x32_bf16(qA1A, kB1, c, 0, 0, 0);
#pragma unroll
        for (int r = 0; r < 4; ++r) sc[n][r] = c[r] * 0.125f;
      }
      if (kt == ktA_max) {
#pragma unroll
        for (int n = 0; n < 8; ++n) {
          const int kg = kb + n * 16 + l16;
#pragma unroll
          for (int r = 0; r < 4; ++r)
            if (kg > qbA + wave * 16 + quad * 4 + r) sc[n][r] = -1.0e30f;
        }
      }
#pragma unroll
      for (int n = 0; n < 8; ++n)
#pragma unroll
        for (int r = 0; r < 4; ++r) {
          float p = __expf(fminf(sc[n][r], 60.0f));
          sc[n][r] = p;
          psA[r] += p;
        }
      {
        const int kb8 = l16 >> 3, lo = l16 & 7;
#pragma unroll
        for (int n = 0; n < 8; ++n) {
          const int chunk = n * 2 + kb8;
#pragma unroll
          for (int r = 0; r < 4; ++r) {
            const int q = quad * 4 + r;
            pw[q * 128 + ((chunk ^ (q & 7)) << 3) + lo] = (__bf16)sc[n][r];
          }
        }
      }
#pragma unroll
      for (int cc = 0; cc < 4; ++cc) {
        bf16x8 pA = *(const bf16x8*)(&pw[l16 * 128 + (((cc * 4 + quad) ^ swq) << 3)]);
#pragma unroll
        for (int nt = 0; nt < 4; ++nt) {
          bf16x8 vB = *(const bf16x8*)(&sV[(nt * 16 + l16) * 128 +
                                           (((cc * 4 + quad) ^ swq) << 3)]);
          OA[nt] = __builtin_amdgcn_mfma_f32_16x16x32_bf16(pA, vB, OA[nt], 0, 0, 0);
        }
      }
    }
  }

  // ---- epilogue
  float invA[4], invB[4];
#pragma unroll
  for (int r = 0; r < 4; ++r) {
    float pa = psA[r], pb = psB[r];
    pa += __shfl_xor(pa, 1); pb += __shfl_xor(pb, 1);
    pa += __shfl_xor(pa, 2); pb += __shfl_xor(pb, 2);
    pa += __shfl_xor(pa, 4); pb += __shfl_xor(pb, 4);
    pa += __shfl_xor(pa, 8); pb += __shfl_xor(pb, 8);
    invA[r] = 1.0f / pa;
    invB[r] = 1.0f / pb;
  }
#pragma unroll
  for (int nt = 0; nt < 4; ++nt) {
#pragma unroll
    for (int r = 0; r < 4; ++r) {
      const int qA = qbA + wave * 16 + quad * 4 + r;
      const int qB = qbB + wave * 16 + quad * 4 + r;
      Aout[((size_t)b * 1024 + qA) * 1024 + h * 64 + nt * 16 + l16] =
          (__bf16)(OA[nt][r] * invA[r]);
      Aout[((size_t)b * 1024 + qB) * 1024 + h * 64 + nt * 16 + l16] =
          (__bf16)(OB[nt][r] * invB[r]);
    }
  }
}

// ---------------- launch ----------------
extern "C" void kernel_launch(void* const* d_in, const int* in_sizes, int n_in,
                              void* d_out, int out_size, void* d_ws,
                              size_t ws_size, hipStream_t stream) {
  const float* x      = (const float*)d_in[0];
  const float* w_attn = (const float*)d_in[1];
  const float* b_attn = (const float*)d_in[2];
  const float* w_proj = (const float*)d_in[3];
  const float* b_proj = (const float*)d_in[4];
  float* out = (float*)d_out;

  char* ws = (char*)d_ws;
  __bf16* WT_attn = (__bf16*)(ws);                  //  6 MB
  __bf16* WT_proj = (__bf16*)(ws + 6291456);        //  2 MB
  __bf16* Xb      = (__bf16*)(ws + 8388608);        //  8 MB (reused as VT)
  __bf16* Qp      = (__bf16*)(ws + 16777216);       //  8 MB [bh][s][64]
  __bf16* Kp      = (__bf16*)(ws + 25165824);       //  8 MB [bh][s][64]
  __bf16* Vr      = (__bf16*)(ws + 33554432);       //  8 MB [s_glob][1024]
  __bf16* Aattn   = (__bf16*)(ws + 41943040);       //  8 MB (end 50 MB)
  __bf16* VT      = Xb;  // x-as-bf16 dead after GEMM1

  prep<<<5120, 256, 0, stream>>>(x, w_attn, w_proj, Xb, WT_attn, WT_proj);
  gemm_qkv8<<<192, 512, 0, stream>>>(Xb, WT_attn, b_attn, Qp, Kp, Vr);
  transpose_v<<<1024, 256, 0, stream>>>(Vr, VT);
  attn_mfma<<<512, 256, 0, stream>>>(Qp, Kp, VT, Aattn);
  gemm_out<<<dim3(8, 32), 256, 0, stream>>>(Aattn, WT_proj, b_proj, out);
}

// Round 2
// 171.676 us; speedup vs baseline: 1.0502x; 1.0418x over previous
//
#include <hip/hip_runtime.h>
#include <hip/hip_bf16.h>

// GPT-2 attention block. Inputs/outputs fp32; internal bf16 MFMA, fp32 accum.
// B=4, S=1024, D=1024, H=16, hd=64.
//
// R14: transpose_v kernel ELIMINATED. gemm_qkv8's V-segment blocks now write
//      VT[bh][d][s] directly via an LDS transpose in the epilogue (smem8 is
//      dead + vmcnt-drained there; 128KB = exactly 256x256 bf16). Vr buffer
//      slot becomes VT (nothing else consumed Vr). Saves one launch + gap
//      and 16MB of HBM traffic. gemm core / attn / prep / gemm_out verbatim
//      from R13.

typedef __bf16 bf16x8 __attribute__((ext_vector_type(8)));
typedef __bf16 bf16x4 __attribute__((ext_vector_type(4)));
typedef float f32x4 __attribute__((ext_vector_type(4)));

__device__ __forceinline__ void load_lds16(const void* g, void* l) {
  __builtin_amdgcn_global_load_lds(
      (const __attribute__((address_space(1))) void*)g,
      (__attribute__((address_space(3))) void*)l, 16, 0, 0);
}

// ---------------- fused prep: transpose w_attn, w_proj; convert x ----------------
__global__ __launch_bounds__(256) void prep(
    const float* __restrict__ x, const float* __restrict__ w_attn,
    const float* __restrict__ w_proj, __bf16* __restrict__ Xb,
    __bf16* __restrict__ WT_attn, __bf16* __restrict__ WT_proj) {
  __shared__ __bf16 tile[32][33];
  const int blk = blockIdx.x;
  const int tid = threadIdx.x;
  if (blk < 4096) {  // transpose (block-uniform branch)
    const float* W;
    __bf16* WT;
    int n0, k0, N;
    if (blk < 3072) {
      W = w_attn; WT = WT_attn; N = 3072;
      n0 = (blk % 96) * 32; k0 = (blk / 96) * 32;
    } else {
      W = w_proj; WT = WT_proj; N = 1024;
      const int t = blk - 3072;
      n0 = (t & 31) * 32; k0 = (t >> 5) * 32;
    }
    const int tx = tid & 31, ty = tid >> 5;
#pragma unroll
    for (int j = 0; j < 32; j += 8)
      tile[ty + j][tx] = (__bf16)W[(size_t)(k0 + ty + j) * N + n0 + tx];
    __syncthreads();
#pragma unroll
    for (int j = 0; j < 32; j += 8)
      WT[(size_t)(n0 + ty + j) * 1024 + k0 + tx] = tile[tx][ty + j];
  } else {  // x -> bf16, 16 elems/thread
    const size_t i = (size_t)(blk - 4096) * 4096 + tid * 16;
    const float4* xp = (const float4*)(x + i);
    float4 a = xp[0], b = xp[1], c = xp[2], d = xp[3];
    bf16x8 o0, o1;
    o0[0] = (__bf16)a.x; o0[1] = (__bf16)a.y; o0[2] = (__bf16)a.z; o0[3] = (__bf16)a.w;
    o0[4] = (__bf16)b.x; o0[5] = (__bf16)b.y; o0[6] = (__bf16)b.z; o0[7] = (__bf16)b.w;
    o1[0] = (__bf16)c.x; o1[1] = (__bf16)c.y; o1[2] = (__bf16)c.z; o1[3] = (__bf16)c.w;
    o1[4] = (__bf16)d.x; o1[5] = (__bf16)d.y; o1[6] = (__bf16)d.z; o1[7] = (__bf16)d.w;
    *(bf16x8*)(Xb + i) = o0;
    *(bf16x8*)(Xb + i + 8) = o1;
  }
}

// ================= GEMM core (R8: BK=32, 16 KB LDS) — used by gemm_out =========
#define GEMM_CORE(A_, BT_, K_)                                                   \
  __shared__ __bf16 sA[128 * 32];                                               \
  __shared__ __bf16 sB[128 * 32];                                               \
  const int tid = threadIdx.x;                                                  \
  const int lane = tid & 63;                                                    \
  const int wave = tid >> 6;                                                    \
  const int waveM = wave >> 1, waveN = wave & 1;                                \
  const int quad = lane >> 4;                                                   \
  const int l16 = lane & 15;                                                    \
  const int rowBase = blockIdx.y * 128;                                         \
  const int colBase = blockIdx.x * 128;                                         \
  const int rIn = lane >> 2;                                                    \
  const int sIn = lane & 3;                                                     \
  const int gc = sIn ^ (rIn & 3) ^ ((rIn >> 2) & 3);                            \
  const int readSlot = quad ^ (l16 & 3) ^ ((l16 >> 2) & 3);                     \
  f32x4 acc[4][4] = {};                                                         \
  for (int k0 = 0; k0 < K_; k0 += 32) {                                         \
    __syncthreads();                                                            \
    _Pragma("unroll") for (int j = 0; j < 2; ++j) {                             \
      const int rb = wave * 32 + j * 16;                                        \
      load_lds16(&A_[(size_t)(rowBase + rb + rIn) * K_ + k0 + gc * 8],          \
                 &sA[rb * 32]);                                                 \
      load_lds16(&BT_[(size_t)(colBase + rb + rIn) * K_ + k0 + gc * 8],         \
                 &sB[rb * 32]);                                                 \
    }                                                                           \
    __syncthreads();                                                            \
    bf16x8 af[4], bfr[4];                                                       \
    _Pragma("unroll") for (int mt = 0; mt < 4; ++mt)                            \
      af[mt] = *(const bf16x8*)(&sA[(waveM * 64 + mt * 16 + l16) * 32 +         \
                                    readSlot * 8]);                             \
    _Pragma("unroll") for (int nt = 0; nt < 4; ++nt)                            \
      bfr[nt] = *(const bf16x8*)(&sB[(waveN * 64 + nt * 16 + l16) * 32 +        \
                                     readSlot * 8]);                            \
    _Pragma("unroll") for (int mt = 0; mt < 4; ++mt)                            \
    _Pragma("unroll") for (int nt = 0; nt < 4; ++nt)                            \
      acc[mt][nt] = __builtin_amdgcn_mfma_f32_16x16x32_bf16(                    \
          af[mt], bfr[nt], acc[mt][nt], 0, 0, 0);                               \
  }

// ================= GEMM1: 256x256 8-phase template (QKV) =================
// 512 threads = 8 waves (2M x 4N). BK=64, double-buffered 128 KB LDS.
// LDS map (bf16 elems): buf b at b*32768; A halves at +0,+8192; B at +16384,+24576.
// Swizzle: slot s of row r holds k-chunk c = s ^ (r&7) (16B chunks).
// Stage schedule per iter t (tiles E=2t in buf0, O=2t+1 in buf1):
//   ph1: O.A1 | ph3: (E+2).B0 | ph4: (E+2).B1,(E+2).A0 + vmcnt(6)
//   ph5: (E+2).A1 | ph7: (O+2).B0 | ph8: (O+2).B1,(O+2).A0 + vmcnt(6)
// vmcnt(6) at ph4 lands everything through this iter's ph1 (all of O);
// vmcnt(6) at ph8 lands through ph5 (all of E+2). Each half is re-staged
// only in a phase strictly after its last reader's lgkmcnt(0).
//
// Epilogue: seg 0/1 -> packed Qp/Kp. seg 2 -> VT[bh][d][s] directly via LDS
// transpose (smem8 reused; element [c][r] stored at c*256 + (r ^ ((c&15)<<4))).

#define BAR8 asm volatile("s_barrier" ::: "memory")
#define LGKM0 asm volatile("s_waitcnt lgkmcnt(0)" ::: "memory")

#define STG(GMAT, GROW0, K0, LOFF)                                             \
  _Pragma("unroll") for (int i_ = 0; i_ < 2; ++i_)                             \
    load_lds16((GMAT) + (size_t)((GROW0) + i_ * 64 + wave * 8 + srow) * 1024 + \
                   (K0) + schunk * 8,                                          \
               smem8 + (LOFF) + (i_ * 64 + wave * 8) * 64);

#define LDA8(BASE, MH)                                                         \
  _Pragma("unroll") for (int m_ = 0; m_ < 4; ++m_)                             \
  _Pragma("unroll") for (int kk_ = 0; kk_ < 2; ++kk_)                          \
    af[m_][kk_] = *(const bf16x8*)((BASE) + ((MH)*64 + m_ * 16 + l16) * 64 +   \
                                   (((kk_ * 4 + quad) ^ rsw) * 8));

#define LDB8(BASE, NLO)                                                        \
  _Pragma("unroll") for (int n_ = 0; n_ < 2; ++n_)                             \
  _Pragma("unroll") for (int kk_ = 0; kk_ < 2; ++kk_)                          \
    bf[(NLO) + n_][kk_] =                                                      \
        *(const bf16x8*)((BASE) + ((waveN & 1) * 64 + ((NLO) + n_) * 16 +      \
                                   l16) * 64 +                                 \
                         (((kk_ * 4 + quad) ^ rsw) * 8));

#define MFMA_HALF(MH, NLO)                                                     \
  __builtin_amdgcn_s_setprio(1);                                               \
  _Pragma("unroll") for (int m_ = 0; m_ < 4; ++m_)                             \
  _Pragma("unroll") for (int n_ = 0; n_ < 2; ++n_) {                           \
    acc[(MH)*4 + m_][(NLO) + n_] = __builtin_amdgcn_mfma_f32_16x16x32_bf16(    \
        af[m_][0], bf[(NLO) + n_][0], acc[(MH)*4 + m_][(NLO) + n_], 0, 0, 0);  \
    acc[(MH)*4 + m_][(NLO) + n_] = __builtin_amdgcn_mfma_f32_16x16x32_bf16(    \
        af[m_][1], bf[(NLO) + n_][1], acc[(MH)*4 + m_][(NLO) + n_], 0, 0, 0);  \
  }                                                                            \
  __builtin_amdgcn_s_setprio(0);

__global__ __launch_bounds__(512, 2) void gemm_qkv8(
    const __bf16* __restrict__ A, const __bf16* __restrict__ BT,
    const float* __restrict__ bias, __bf16* __restrict__ Qp,
    __bf16* __restrict__ Kp, __bf16* __restrict__ Vt) {
  __shared__ __bf16 smem8[65536];  // 128 KB
  const int tid = threadIdx.x;
  const int lane = tid & 63;
  const int wave = tid >> 6;
  const int waveM = wave >> 2;  // 0..1
  const int waveN = wave & 3;   // 0..3
  const int l16 = lane & 15;
  const int quad = lane >> 4;
  const int rsw = l16 & 7;
  const int srow = lane >> 3;            // staging row-in-8
  const int schunk = (lane & 7) ^ srow;  // pre-swizzled source chunk

  // XCD-aware bijective swizzle: 192 blocks = 8 XCDs x 24
  const int bid = blockIdx.x;
  const int swz = (bid & 7) * 24 + (bid >> 3);
  const int tm = swz / 12, tn = swz - (swz / 12) * 12;
  const int rowBase = tm * 256;
  const int colBase = tn * 256;

  const __bf16* aRd = smem8 + waveM * 8192;                 // buf0 A (own half)
  const __bf16* bRd = smem8 + 16384 + (waveN >> 1) * 8192;  // buf0 B (own half)

  f32x4 acc[8][4] = {};
  bf16x8 af[4][2], bf[4][2];

  // ---- prologue: stage T0 fully, T1 {B0,B1,A0}
  STG(A, rowBase, 0, 0);
  STG(A, rowBase + 128, 0, 8192);
  STG(BT, colBase, 0, 16384);
  STG(BT, colBase + 128, 0, 24576);
  STG(BT, colBase, 64, 32768 + 16384);
  STG(BT, colBase + 128, 64, 32768 + 24576);
  STG(A, rowBase, 64, 32768);
  asm volatile("s_waitcnt vmcnt(6)" ::: "memory");  // T0 landed
  BAR8;

  for (int t = 0; t < 8; ++t) {
    const int kO = t * 128 + 64;   // odd tile K offset (for O.A1 stage)
    const int kS2 = t * 128 + 128; // prefetch tile for buf0
    const int kS3 = t * 128 + 192; // prefetch tile for buf1
    const bool s2 = kS2 < 1024;
    const bool s3 = kS3 < 1024;

    // ---- phase 1: read E.A-mh0 + E.B-n01 ; stage O.A1
    LDA8(aRd, 0);
    LDB8(bRd, 0);
    STG(A, rowBase + 128, kO, 32768 + 8192);
    BAR8; LGKM0;
    MFMA_HALF(0, 0);
    BAR8;

    // ---- phase 2: read E.B-n23
    LDB8(bRd, 2);
    BAR8; LGKM0;
    MFMA_HALF(0, 2);
    BAR8;

    // ---- phase 3: read E.A-mh1 ; stage (E+2).B0
    LDA8(aRd, 1);
    if (s2) { STG(BT, colBase, kS2, 16384); }
    BAR8; LGKM0;
    MFMA_HALF(1, 2);
    BAR8;

    // ---- phase 4: stage (E+2).B1 + (E+2).A0 ; counted vmcnt
    if (s2) {
      STG(BT, colBase + 128, kS2, 24576);
      STG(A, rowBase, kS2, 0);
      asm volatile("s_waitcnt vmcnt(6)" ::: "memory");  // all of O landed
    } else {
      asm volatile("s_waitcnt vmcnt(0)" ::: "memory");  // last iter: drain
    }
    BAR8;
    MFMA_HALF(1, 0);
    BAR8;

    // ---- phase 5: read O.A-mh0 + O.B-n01 ; stage (E+2).A1
    LDA8(aRd + 32768, 0);
    LDB8(bRd + 32768, 0);
    if (s2) { STG(A, rowBase + 128, kS2, 8192); }
    BAR8; LGKM0;
    MFMA_HALF(0, 0);
    BAR8;

    // ---- phase 6: read O.B-n23
    LDB8(bRd + 32768, 2);
    BAR8; LGKM0;
    MFMA_HALF(0, 2);
    BAR8;

    // ---- phase 7: read O.A-mh1 ; stage (O+2).B0
    LDA8(aRd + 32768, 1);
    if (s3) { STG(BT, colBase, kS3, 32768 + 16384); }
    BAR8; LGKM0;
    MFMA_HALF(1, 2);
    BAR8;

    // ---- phase 8: stage (O+2).B1 + (O+2).A0 ; counted vmcnt
    if (s3) {
      STG(BT, colBase + 128, kS3, 32768 + 24576);
      STG(A, rowBase, kS3, 32768);
    }
    asm volatile("s_waitcnt vmcnt(6)" ::: "memory");  // all of E+2 landed
    BAR8;
    MFMA_HALF(1, 0);
    BAR8;
  }

  const int seg = colBase >> 10;  // 0=Q 1=K 2=V (block-uniform)
  if (seg == 2) {
    // ---- V epilogue: transpose 256x256 tile in LDS, write VT[bh][d][s].
    // smem8 is dead here (phase-4 t=7 did vmcnt(0); final BAR8 passed).
    // Store row r of col c at elem c*256 + (r ^ ((c&15)<<4)); XOR bits 4-7
    // are disjoint from in-chunk bits, so 8B stores / 16B reads stay
    // contiguous and the mapping is bijective.
#pragma unroll
    for (int mm = 0; mm < 8; ++mm) {
      const int r0 = waveM * 128 + mm * 16 + quad * 4;
#pragma unroll
      for (int n = 0; n < 4; ++n) {
        const int cR = waveN * 64 + n * 16 + l16;
        const float bv = bias[colBase + cR];
        bf16x4 pk;
#pragma unroll
        for (int r = 0; r < 4; ++r) pk[r] = (__bf16)(acc[mm][n][r] + bv);
        *(bf16x4*)(&smem8[cR * 256 + (r0 ^ (l16 << 4))]) = pk;
      }
    }
    __syncthreads();
    const int b_ = rowBase >> 10;
    const int s0 = rowBase & 1023;
    const int hBase = (colBase & 1023) >> 6;
    const int ch = lane & 31;
#pragma unroll
    for (int p = 0; p < 16; ++p) {
      const int c = p * 16 + wave * 2 + (lane >> 5);
      bf16x8 v =
          *(const bf16x8*)(&smem8[c * 256 + ((ch * 8) ^ ((c & 15) << 4))]);
      const int bhd = (b_ * 16 + hBase + (c >> 6)) * 64 + (c & 63);
      *(bf16x8*)(&Vt[(size_t)bhd * 1024 + s0 + ch * 8]) = v;
    }
  } else {
    // ---- Q/K epilogue: packed [bh][s][64]
#pragma unroll
    for (int mm = 0; mm < 8; ++mm) {
      const int row0 = rowBase + waveM * 128 + mm * 16 + quad * 4;
#pragma unroll
      for (int n = 0; n < 4; ++n) {
        const int col = colBase + waveN * 64 + n * 16 + l16;
        const float bv = bias[col];
        const int cc = col & 1023;
        __bf16* dst = (seg == 0) ? Qp : Kp;
#pragma unroll
        for (int r = 0; r < 4; ++r) {
          const int row = row0 + r;
          const float v = acc[mm][n][r] + bv;
          const int bh = ((row >> 10) << 4) + (cc >> 6);
          dst[((size_t)bh << 16) + (size_t)(row & 1023) * 64 + (cc & 63)] =
              (__bf16)v;
        }
      }
    }
  }
}

// ---------------- GEMM2: out = A @ WT^T + bias (fp32 out) ----------------
__global__ __launch_bounds__(256) void gemm_out(
    const __bf16* __restrict__ A, const __bf16* __restrict__ BT,
    const float* __restrict__ bias, float* __restrict__ C) {
  GEMM_CORE(A, BT, 1024)
#pragma unroll
  for (int mt = 0; mt < 4; ++mt) {
    const int row = rowBase + waveM * 64 + mt * 16 + quad * 4;
#pragma unroll
    for (int nt = 0; nt < 4; ++nt) {
      const int col = colBase + waveN * 64 + nt * 16 + l16;
      const float bv = bias[col];
#pragma unroll
      for (int r = 0; r < 4; ++r)
        C[(size_t)(row + r) * 1024 + col] = acc[mt][nt][r] + bv;
    }
  }
}

// ---------------- paired flash attention (R9 kernel, verbatim) ----------------
__global__ __launch_bounds__(256) void attn_mfma(
    const __bf16* __restrict__ Qp, const __bf16* __restrict__ Kp,
    const __bf16* __restrict__ VT, __bf16* __restrict__ Aout) {
  __shared__ __bf16 sK[128 * 64];      // 16 KB, swizzled packed K lines
  __shared__ __bf16 sV[64 * 128];      // 16 KB, swizzled V^T
  __shared__ __bf16 sP[4 * 16 * 128];  // 16 KB, per-wave P regions

  const int tid = threadIdx.x;
  const int lane = tid & 63;
  const int wave = tid >> 6;
  const int quad = lane >> 4;
  const int l16 = lane & 15;
  const int swq = l16 & 7;

  const int bh = blockIdx.x >> 3;
  const int pr = blockIdx.x & 7;
  const int b = bh >> 4, h = bh & 15;
  const int qbA = pr * 64, qbB = (15 - pr) * 64;
  const int ktA_max = pr >> 1, ktB_max = (15 - pr) >> 1;

  const __bf16* Qb = Qp + ((size_t)bh << 16);
  const __bf16* Kb = Kp + ((size_t)bh << 16);
  const __bf16* VTb = VT + (size_t)bh * 64 * 1024;

  bf16x8 qA0A, qA1A, qA0B, qA1B;
  {
    const __bf16* qr = Qb + (size_t)(qbA + wave * 16 + l16) * 64 + quad * 8;
    qA0A = *(const bf16x8*)qr;
    qA1A = *(const bf16x8*)(qr + 32);
    qr = Qb + (size_t)(qbB + wave * 16 + l16) * 64 + quad * 8;
    qA0B = *(const bf16x8*)qr;
    qA1B = *(const bf16x8*)(qr + 32);
  }

  f32x4 OA[4] = {}, OB[4] = {};
  float psA[4] = {0.f, 0.f, 0.f, 0.f}, psB[4] = {0.f, 0.f, 0.f, 0.f};
  __bf16* pw = sP + wave * 2048;

  for (int kt = 0; kt <= ktB_max; ++kt) {
    const int kb = kt * 128;
    __syncthreads();  // prior iter's sK/sV reads complete

    // ---- DMA stage K: sK[key][slot s] = line chunk s^(key&7)
#pragma unroll
    for (int i = 0; i < 4; ++i) {
      const int rb = wave * 32 + i * 8;
      load_lds16(Kb + (size_t)(kb + rb + (lane >> 3)) * 64 +
                     (((lane & 7) ^ ((lane >> 3) & 7)) << 3),
                 &sK[rb * 64]);
    }
    // ---- DMA stage V^T: sV[d][slot s] = key-chunk s^(d&7)
#pragma unroll
    for (int i = 0; i < 4; ++i) {
      const int db = wave * 16 + i * 4;
      const int d = db + (lane >> 4);
      load_lds16(VTb + (size_t)d * 1024 + kb + (((lane & 15) ^ (d & 7)) << 3),
                 &sV[db * 128]);
    }
    __syncthreads();  // staged

    // ================= q-tile B (always active) =================
    {
      float sc[8][4];
#pragma unroll
      for (int n = 0; n < 8; ++n) {
        const int key = n * 16 + l16;
        bf16x8 kB0 = *(const bf16x8*)(&sK[key * 64 + ((quad ^ swq) << 3)]);
        bf16x8 kB1 = *(const bf16x8*)(&sK[key * 64 + (((quad + 4) ^ swq) << 3)]);
        f32x4 c = {};
        c = __builtin_amdgcn_mfma_f32_16x16x32_bf16(qA0B, kB0, c, 0, 0, 0);
        c = __builtin_amdgcn_mfma_f32_16x16x32_bf16(qA1B, kB1, c, 0, 0, 0);
#pragma unroll
        for (int r = 0; r < 4; ++r) sc[n][r] = c[r] * 0.125f;
      }
      if (kt == ktB_max) {
#pragma unroll
        for (int n = 0; n < 8; ++n) {
          const int kg = kb + n * 16 + l16;
#pragma unroll
          for (int r = 0; r < 4; ++r)
            if (kg > qbB + wave * 16 + quad * 4 + r) sc[n][r] = -1.0e30f;
        }
      }
#pragma unroll
      for (int n = 0; n < 8; ++n)
#pragma unroll
        for (int r = 0; r < 4; ++r) {
          float p = __expf(fminf(sc[n][r], 60.0f));
          sc[n][r] = p;
          psB[r] += p;
        }
      {
        const int kb8 = l16 >> 3, lo = l16 & 7;
#pragma unroll
        for (int n = 0; n < 8; ++n) {
          const int chunk = n * 2 + kb8;
#pragma unroll
          for (int r = 0; r < 4; ++r) {
            const int q = quad * 4 + r;
            pw[q * 128 + ((chunk ^ (q & 7)) << 3) + lo] = (__bf16)sc[n][r];
          }
        }
      }
#pragma unroll
      for (int cc = 0; cc < 4; ++cc) {
        bf16x8 pA = *(const bf16x8*)(&pw[l16 * 128 + (((cc * 4 + quad) ^ swq) << 3)]);
#pragma unroll
        for (int nt = 0; nt < 4; ++nt) {
          bf16x8 vB = *(const bf16x8*)(&sV[(nt * 16 + l16) * 128 +
                                           (((cc * 4 + quad) ^ swq) << 3)]);
          OB[nt] = __builtin_amdgcn_mfma_f32_16x16x32_bf16(pA, vB, OB[nt], 0, 0, 0);
        }
      }
    }

    // ================= q-tile A (active while kt <= ktA_max) =================
    if (kt <= ktA_max) {
      float sc[8][4];
#pragma unroll
      for (int n = 0; n < 8; ++n) {
        const int key = n * 16 + l16;
        bf16x8 kB0 = *(const bf16x8*)(&sK[key * 64 + ((quad ^ swq) << 3)]);
        bf16x8 kB1 = *(const bf16x8*)(&sK[key * 64 + (((quad + 4) ^ swq) << 3)]);
        f32x4 c = {};
        c = __builtin_amdgcn_mfma_f32_16x16x32_bf16(qA0A, kB0, c, 0, 0, 0);
        c = __builtin_amdgcn_mfma_f32_16x16x32_bf16(qA1A, kB1, c, 0, 0, 0);
#pragma unroll
        for (int r = 0; r < 4; ++r) sc[n][r] = c[r] * 0.125f;
      }
      if (kt == ktA_max) {
#pragma unroll
        for (int n = 0; n < 8; ++n) {
          const int kg = kb + n * 16 + l16;
#pragma unroll
          for (int r = 0; r < 4; ++r)
            if (kg > qbA + wave * 16 + quad * 4 + r) sc[n][r] = -1.0e30f;
        }
      }
#pragma unroll
      for (int n = 0; n < 8; ++n)
#pragma unroll
        for (int r = 0; r < 4; ++r) {
          float p = __expf(fminf(sc[n][r], 60.0f));
          sc[n][r] = p;
          psA[r] += p;
        }
      {
        const int kb8 = l16 >> 3, lo = l16 & 7;
#pragma unroll
        for (int n = 0; n < 8; ++n) {
          const int chunk = n * 2 + kb8;
#pragma unroll
          for (int r = 0; r < 4; ++r) {
            const int q = quad * 4 + r;
            pw[q * 128 + ((chunk ^ (q & 7)) << 3) + lo] = (__bf16)sc[n][r];
          }
        }
      }
#pragma unroll
      for (int cc = 0; cc < 4; ++cc) {
        bf16x8 pA = *(const bf16x8*)(&pw[l16 * 128 + (((cc * 4 + quad) ^ swq) << 3)]);
#pragma unroll
        for (int nt = 0; nt < 4; ++nt) {
          bf16x8 vB = *(const bf16x8*)(&sV[(nt * 16 + l16) * 128 +
                                           (((cc * 4 + quad) ^ swq) << 3)]);
          OA[nt] = __builtin_amdgcn_mfma_f32_16x16x32_bf16(pA, vB, OA[nt], 0, 0, 0);
        }
      }
    }
  }

  // ---- epilogue
  float invA[4], invB[4];
#pragma unroll
  for (int r = 0; r < 4; ++r) {
    float pa = psA[r], pb = psB[r];
    pa += __shfl_xor(pa, 1); pb += __shfl_xor(pb, 1);
    pa += __shfl_xor(pa, 2); pb += __shfl_xor(pb, 2);
    pa += __shfl_xor(pa, 4); pb += __shfl_xor(pb, 4);
    pa += __shfl_xor(pa, 8); pb += __shfl_xor(pb, 8);
    invA[r] = 1.0f / pa;
    invB[r] = 1.0f / pb;
  }
#pragma unroll
  for (int nt = 0; nt < 4; ++nt) {
#pragma unroll
    for (int r = 0; r < 4; ++r) {
      const int qA = qbA + wave * 16 + quad * 4 + r;
      const int qB = qbB + wave * 16 + quad * 4 + r;
      Aout[((size_t)b * 1024 + qA) * 1024 + h * 64 + nt * 16 + l16] =
          (__bf16)(OA[nt][r] * invA[r]);
      Aout[((size_t)b * 1024 + qB) * 1024 + h * 64 + nt * 16 + l16] =
          (__bf16)(OB[nt][r] * invB[r]);
    }
  }
}

// ---------------- launch ----------------
extern "C" void kernel_launch(void* const* d_in, const int* in_sizes, int n_in,
                              void* d_out, int out_size, void* d_ws,
                              size_t ws_size, hipStream_t stream) {
  const float* x      = (const float*)d_in[0];
  const float* w_attn = (const float*)d_in[1];
  const float* b_attn = (const float*)d_in[2];
  const float* w_proj = (const float*)d_in[3];
  const float* b_proj = (const float*)d_in[4];
  float* out = (float*)d_out;

  char* ws = (char*)d_ws;
  __bf16* WT_attn = (__bf16*)(ws);                  //  6 MB
  __bf16* WT_proj = (__bf16*)(ws + 6291456);        //  2 MB
  __bf16* Xb      = (__bf16*)(ws + 8388608);        //  8 MB
  __bf16* Qp      = (__bf16*)(ws + 16777216);       //  8 MB [bh][s][64]
  __bf16* Kp      = (__bf16*)(ws + 25165824);       //  8 MB [bh][s][64]
  __bf16* VT      = (__bf16*)(ws + 33554432);       //  8 MB [bh][d][s] (was Vr)
  __bf16* Aattn   = (__bf16*)(ws + 41943040);       //  8 MB (end 50 MB)

  prep<<<5120, 256, 0, stream>>>(x, w_attn, w_proj, Xb, WT_attn, WT_proj);
  gemm_qkv8<<<192, 512, 0, stream>>>(Xb, WT_attn, b_attn, Qp, Kp, VT);
  attn_mfma<<<512, 256, 0, stream>>>(Qp, Kp, VT, Aattn);
  gemm_out<<<dim3(8, 32), 256, 0, stream>>>(Aattn, WT_proj, b_proj, out);
}

// Round 3
// 170.859 us; speedup vs baseline: 1.0552x; 1.0048x over previous
//
#include <hip/hip_runtime.h>
#include <hip/hip_bf16.h>

// GPT-2 attention block. Inputs/outputs fp32; internal bf16 MFMA, fp32 accum.
// B=4, S=1024, D=1024, H=16, hd=64.
//
// R15: kill the 2-phase barrier-drain stalls in attn_mfma and gemm_out.
//  - attn_mfma: K/V double-buffered (80 KB LDS; still 2 blocks/CU since the
//    512-block grid is the limiter), next tile's global_load_lds issued
//    BEFORE compute, raw s_barrier with vmcnt(0) placed AFTER compute so the
//    drain lands under MFMA+softmax. s_setprio(1) around MFMA clusters.
//  - gemm_out: 3-buffer depth-2 pipeline (48 KB LDS), counted vmcnt(4)
//    (4 loads/stage/wave), fully unrolled 32-iter K-loop.
//  prep / gemm_qkv8 (8-phase 256^2 + fused V-transpose epilogue) from R14.

typedef __bf16 bf16x8 __attribute__((ext_vector_type(8)));
typedef __bf16 bf16x4 __attribute__((ext_vector_type(4)));
typedef float f32x4 __attribute__((ext_vector_type(4)));

__device__ __forceinline__ void load_lds16(const void* g, void* l) {
  __builtin_amdgcn_global_load_lds(
      (const __attribute__((address_space(1))) void*)g,
      (__attribute__((address_space(3))) void*)l, 16, 0, 0);
}

#define BAR8 asm volatile("s_barrier" ::: "memory")
#define LGKM0 asm volatile("s_waitcnt lgkmcnt(0)" ::: "memory")

// ---------------- fused prep: transpose w_attn, w_proj; convert x ----------------
__global__ __launch_bounds__(256) void prep(
    const float* __restrict__ x, const float* __restrict__ w_attn,
    const float* __restrict__ w_proj, __bf16* __restrict__ Xb,
    __bf16* __restrict__ WT_attn, __bf16* __restrict__ WT_proj) {
  __shared__ __bf16 tile[32][33];
  const int blk = blockIdx.x;
  const int tid = threadIdx.x;
  if (blk < 4096) {  // transpose (block-uniform branch)
    const float* W;
    __bf16* WT;
    int n0, k0, N;
    if (blk < 3072) {
      W = w_attn; WT = WT_attn; N = 3072;
      n0 = (blk % 96) * 32; k0 = (blk / 96) * 32;
    } else {
      W = w_proj; WT = WT_proj; N = 1024;
      const int t = blk - 3072;
      n0 = (t & 31) * 32; k0 = (t >> 5) * 32;
    }
    const int tx = tid & 31, ty = tid >> 5;
#pragma unroll
    for (int j = 0; j < 32; j += 8)
      tile[ty + j][tx] = (__bf16)W[(size_t)(k0 + ty + j) * N + n0 + tx];
    __syncthreads();
#pragma unroll
    for (int j = 0; j < 32; j += 8)
      WT[(size_t)(n0 + ty + j) * 1024 + k0 + tx] = tile[tx][ty + j];
  } else {  // x -> bf16, 16 elems/thread
    const size_t i = (size_t)(blk - 4096) * 4096 + tid * 16;
    const float4* xp = (const float4*)(x + i);
    float4 a = xp[0], b = xp[1], c = xp[2], d = xp[3];
    bf16x8 o0, o1;
    o0[0] = (__bf16)a.x; o0[1] = (__bf16)a.y; o0[2] = (__bf16)a.z; o0[3] = (__bf16)a.w;
    o0[4] = (__bf16)b.x; o0[5] = (__bf16)b.y; o0[6] = (__bf16)b.z; o0[7] = (__bf16)b.w;
    o1[0] = (__bf16)c.x; o1[1] = (__bf16)c.y; o1[2] = (__bf16)c.z; o1[3] = (__bf16)c.w;
    o1[4] = (__bf16)d.x; o1[5] = (__bf16)d.y; o1[6] = (__bf16)d.z; o1[7] = (__bf16)d.w;
    *(bf16x8*)(Xb + i) = o0;
    *(bf16x8*)(Xb + i + 8) = o1;
  }
}

// ================= GEMM1: 256x256 8-phase template (QKV) =================
// 512 threads = 8 waves (2M x 4N). BK=64, double-buffered 128 KB LDS.
// LDS map (bf16 elems): buf b at b*32768; A halves at +0,+8192; B at +16384,+24576.
// Swizzle: slot s of row r holds k-chunk c = s ^ (r&7) (16B chunks).
// Stage schedule per iter t (tiles E=2t in buf0, O=2t+1 in buf1):
//   ph1: O.A1 | ph3: (E+2).B0 | ph4: (E+2).B1,(E+2).A0 + vmcnt(6)
//   ph5: (E+2).A1 | ph7: (O+2).B0 | ph8: (O+2).B1,(O+2).A0 + vmcnt(6)
// Epilogue: seg 0/1 -> packed Qp/Kp. seg 2 -> VT[bh][d][s] directly via LDS
// transpose (smem8 reused; element [c][r] stored at c*256 + (r ^ ((c&15)<<4))).

#define STG(GMAT, GROW0, K0, LOFF)                                             \
  _Pragma("unroll") for (int i_ = 0; i_ < 2; ++i_)                             \
    load_lds16((GMAT) + (size_t)((GROW0) + i_ * 64 + wave * 8 + srow) * 1024 + \
                   (K0) + schunk * 8,                                          \
               smem8 + (LOFF) + (i_ * 64 + wave * 8) * 64);

#define LDA8(BASE, MH)                                                         \
  _Pragma("unroll") for (int m_ = 0; m_ < 4; ++m_)                             \
  _Pragma("unroll") for (int kk_ = 0; kk_ < 2; ++kk_)                          \
    af[m_][kk_] = *(const bf16x8*)((BASE) + ((MH)*64 + m_ * 16 + l16) * 64 +   \
                                   (((kk_ * 4 + quad) ^ rsw) * 8));

#define LDB8(BASE, NLO)                                                        \
  _Pragma("unroll") for (int n_ = 0; n_ < 2; ++n_)                             \
  _Pragma("unroll") for (int kk_ = 0; kk_ < 2; ++kk_)                          \
    bf[(NLO) + n_][kk_] =                                                      \
        *(const bf16x8*)((BASE) + ((waveN & 1) * 64 + ((NLO) + n_) * 16 +      \
                                   l16) * 64 +                                 \
                         (((kk_ * 4 + quad) ^ rsw) * 8));

#define MFMA_HALF(MH, NLO)                                                     \
  __builtin_amdgcn_s_setprio(1);                                               \
  _Pragma("unroll") for (int m_ = 0; m_ < 4; ++m_)                             \
  _Pragma("unroll") for (int n_ = 0; n_ < 2; ++n_) {                           \
    acc[(MH)*4 + m_][(NLO) + n_] = __builtin_amdgcn_mfma_f32_16x16x32_bf16(    \
        af[m_][0], bf[(NLO) + n_][0], acc[(MH)*4 + m_][(NLO) + n_], 0, 0, 0);  \
    acc[(MH)*4 + m_][(NLO) + n_] = __builtin_amdgcn_mfma_f32_16x16x32_bf16(    \
        af[m_][1], bf[(NLO) + n_][1], acc[(MH)*4 + m_][(NLO) + n_], 0, 0, 0);  \
  }                                                                            \
  __builtin_amdgcn_s_setprio(0);

__global__ __launch_bounds__(512, 2) void gemm_qkv8(
    const __bf16* __restrict__ A, const __bf16* __restrict__ BT,
    const float* __restrict__ bias, __bf16* __restrict__ Qp,
    __bf16* __restrict__ Kp, __bf16* __restrict__ Vt) {
  __shared__ __bf16 smem8[65536];  // 128 KB
  const int tid = threadIdx.x;
  const int lane = tid & 63;
  const int wave = tid >> 6;
  const int waveM = wave >> 2;  // 0..1
  const int waveN = wave & 3;   // 0..3
  const int l16 = lane & 15;
  const int quad = lane >> 4;
  const int rsw = l16 & 7;
  const int srow = lane >> 3;            // staging row-in-8
  const int schunk = (lane & 7) ^ srow;  // pre-swizzled source chunk

  // XCD-aware bijective swizzle: 192 blocks = 8 XCDs x 24
  const int bid = blockIdx.x;
  const int swz = (bid & 7) * 24 + (bid >> 3);
  const int tm = swz / 12, tn = swz - (swz / 12) * 12;
  const int rowBase = tm * 256;
  const int colBase = tn * 256;

  const __bf16* aRd = smem8 + waveM * 8192;                 // buf0 A (own half)
  const __bf16* bRd = smem8 + 16384 + (waveN >> 1) * 8192;  // buf0 B (own half)

  f32x4 acc[8][4] = {};
  bf16x8 af[4][2], bf[4][2];

  // ---- prologue: stage T0 fully, T1 {B0,B1,A0}
  STG(A, rowBase, 0, 0);
  STG(A, rowBase + 128, 0, 8192);
  STG(BT, colBase, 0, 16384);
  STG(BT, colBase + 128, 0, 24576);
  STG(BT, colBase, 64, 32768 + 16384);
  STG(BT, colBase + 128, 64, 32768 + 24576);
  STG(A, rowBase, 64, 32768);
  asm volatile("s_waitcnt vmcnt(6)" ::: "memory");  // T0 landed
  BAR8;

  for (int t = 0; t < 8; ++t) {
    const int kO = t * 128 + 64;   // odd tile K offset (for O.A1 stage)
    const int kS2 = t * 128 + 128; // prefetch tile for buf0
    const int kS3 = t * 128 + 192; // prefetch tile for buf1
    const bool s2 = kS2 < 1024;
    const bool s3 = kS3 < 1024;

    // ---- phase 1: read E.A-mh0 + E.B-n01 ; stage O.A1
    LDA8(aRd, 0);
    LDB8(bRd, 0);
    STG(A, rowBase + 128, kO, 32768 + 8192);
    BAR8; LGKM0;
    MFMA_HALF(0, 0);
    BAR8;

    // ---- phase 2: read E.B-n23
    LDB8(bRd, 2);
    BAR8; LGKM0;
    MFMA_HALF(0, 2);
    BAR8;

    // ---- phase 3: read E.A-mh1 ; stage (E+2).B0
    LDA8(aRd, 1);
    if (s2) { STG(BT, colBase, kS2, 16384); }
    BAR8; LGKM0;
    MFMA_HALF(1, 2);
    BAR8;

    // ---- phase 4: stage (E+2).B1 + (E+2).A0 ; counted vmcnt
    if (s2) {
      STG(BT, colBase + 128, kS2, 24576);
      STG(A, rowBase, kS2, 0);
      asm volatile("s_waitcnt vmcnt(6)" ::: "memory");  // all of O landed
    } else {
      asm volatile("s_waitcnt vmcnt(0)" ::: "memory");  // last iter: drain
    }
    BAR8;
    MFMA_HALF(1, 0);
    BAR8;

    // ---- phase 5: read O.A-mh0 + O.B-n01 ; stage (E+2).A1
    LDA8(aRd + 32768, 0);
    LDB8(bRd + 32768, 0);
    if (s2) { STG(A, rowBase + 128, kS2, 8192); }
    BAR8; LGKM0;
    MFMA_HALF(0, 0);
    BAR8;

    // ---- phase 6: read O.B-n23
    LDB8(bRd + 32768, 2);
    BAR8; LGKM0;
    MFMA_HALF(0, 2);
    BAR8;

    // ---- phase 7: read O.A-mh1 ; stage (O+2).B0
    LDA8(aRd + 32768, 1);
    if (s3) { STG(BT, colBase, kS3, 32768 + 16384); }
    BAR8; LGKM0;
    MFMA_HALF(1, 2);
    BAR8;

    // ---- phase 8: stage (O+2).B1 + (O+2).A0 ; counted vmcnt
    if (s3) {
      STG(BT, colBase + 128, kS3, 32768 + 24576);
      STG(A, rowBase, kS3, 32768);
    }
    asm volatile("s_waitcnt vmcnt(6)" ::: "memory");  // all of E+2 landed
    BAR8;
    MFMA_HALF(1, 0);
    BAR8;
  }

  const int seg = colBase >> 10;  // 0=Q 1=K 2=V (block-uniform)
  if (seg == 2) {
    // ---- V epilogue: transpose 256x256 tile in LDS, write VT[bh][d][s].
    // smem8 is dead here (phase-4 t=7 did vmcnt(0); final BAR8 passed).
#pragma unroll
    for (int mm = 0; mm < 8; ++mm) {
      const int r0 = waveM * 128 + mm * 16 + quad * 4;
#pragma unroll
      for (int n = 0; n < 4; ++n) {
        const int cR = waveN * 64 + n * 16 + l16;
        const float bv = bias[colBase + cR];
        bf16x4 pk;
#pragma unroll
        for (int r = 0; r < 4; ++r) pk[r] = (__bf16)(acc[mm][n][r] + bv);
        *(bf16x4*)(&smem8[cR * 256 + (r0 ^ (l16 << 4))]) = pk;
      }
    }
    __syncthreads();
    const int b_ = rowBase >> 10;
    const int s0 = rowBase & 1023;
    const int hBase = (colBase & 1023) >> 6;
    const int ch = lane & 31;
#pragma unroll
    for (int p = 0; p < 16; ++p) {
      const int c = p * 16 + wave * 2 + (lane >> 5);
      bf16x8 v =
          *(const bf16x8*)(&smem8[c * 256 + ((ch * 8) ^ ((c & 15) << 4))]);
      const int bhd = (b_ * 16 + hBase + (c >> 6)) * 64 + (c & 63);
      *(bf16x8*)(&Vt[(size_t)bhd * 1024 + s0 + ch * 8]) = v;
    }
  } else {
    // ---- Q/K epilogue: packed [bh][s][64]
#pragma unroll
    for (int mm = 0; mm < 8; ++mm) {
      const int row0 = rowBase + waveM * 128 + mm * 16 + quad * 4;
#pragma unroll
      for (int n = 0; n < 4; ++n) {
        const int col = colBase + waveN * 64 + n * 16 + l16;
        const float bv = bias[col];
        const int cc = col & 1023;
        __bf16* dst = (seg == 0) ? Qp : Kp;
#pragma unroll
        for (int r = 0; r < 4; ++r) {
          const int row = row0 + r;
          const float v = acc[mm][n][r] + bv;
          const int bh = ((row >> 10) << 4) + (cc >> 6);
          dst[((size_t)bh << 16) + (size_t)(row & 1023) * 64 + (cc & 63)] =
              (__bf16)v;
        }
      }
    }
  }
}

// ---------------- GEMM2: out = A @ WT^T + bias, depth-2 pipelined ----------------
__global__ __launch_bounds__(256) void gemm_out(
    const __bf16* __restrict__ A, const __bf16* __restrict__ BT,
    const float* __restrict__ bias, float* __restrict__ C) {
  __shared__ __bf16 sA[3][128 * 32];  // 24 KB
  __shared__ __bf16 sB[3][128 * 32];  // 24 KB
  const int tid = threadIdx.x;
  const int lane = tid & 63;
  const int wave = tid >> 6;
  const int waveM = wave >> 1, waveN = wave & 1;
  const int quad = lane >> 4;
  const int l16 = lane & 15;
  const int rowBase = blockIdx.y * 128;
  const int colBase = blockIdx.x * 128;
  const int rIn = lane >> 2;
  const int sIn = lane & 3;
  const int gc = sIn ^ (rIn & 3) ^ ((rIn >> 2) & 3);
  const int readSlot = quad ^ (l16 & 3) ^ ((l16 >> 2) & 3);
  f32x4 acc[4][4] = {};

#define GO_STAGE(bi, k0_)                                                      \
  _Pragma("unroll") for (int j_ = 0; j_ < 2; ++j_) {                           \
    const int rb = wave * 32 + j_ * 16;                                        \
    load_lds16(&A[(size_t)(rowBase + rb + rIn) * 1024 + (k0_) + gc * 8],       \
               &sA[bi][rb * 32]);                                              \
    load_lds16(&BT[(size_t)(colBase + rb + rIn) * 1024 + (k0_) + gc * 8],      \
               &sB[bi][rb * 32]);                                              \
  }

  // prologue: tiles 0 and 1 in flight (4 loads each per wave)
  GO_STAGE(0, 0);
  GO_STAGE(1, 32);
  asm volatile("s_waitcnt vmcnt(4)" ::: "memory");  // tile 0 landed
  BAR8;

#pragma unroll
  for (int i = 0; i < 32; ++i) {
    if (i + 2 < 32) { GO_STAGE((i + 2) % 3, (i + 2) * 32); }
    const __bf16* sAc = sA[i % 3];
    const __bf16* sBc = sB[i % 3];
    bf16x8 af[4], bfr[4];
#pragma unroll
    for (int mt = 0; mt < 4; ++mt)
      af[mt] = *(const bf16x8*)(&sAc[(waveM * 64 + mt * 16 + l16) * 32 +
                                     readSlot * 8]);
#pragma unroll
    for (int nt = 0; nt < 4; ++nt)
      bfr[nt] = *(const bf16x8*)(&sBc[(waveN * 64 + nt * 16 + l16) * 32 +
                                      readSlot * 8]);
    __builtin_amdgcn_s_setprio(1);
#pragma unroll
    for (int mt = 0; mt < 4; ++mt)
#pragma unroll
      for (int nt = 0; nt < 4; ++nt)
        acc[mt][nt] = __builtin_amdgcn_mfma_f32_16x16x32_bf16(
            af[mt], bfr[nt], acc[mt][nt], 0, 0, 0);
    __builtin_amdgcn_s_setprio(0);
    if (i + 1 < 32) {
      if (i + 2 < 32) {
        asm volatile("s_waitcnt vmcnt(4)" ::: "memory");  // tile i+1 landed
      } else {
        asm volatile("s_waitcnt vmcnt(0)" ::: "memory");  // drain last stage
      }
      BAR8;
    }
  }

#pragma unroll
  for (int mt = 0; mt < 4; ++mt) {
    const int row = rowBase + waveM * 64 + mt * 16 + quad * 4;
#pragma unroll
    for (int nt = 0; nt < 4; ++nt) {
      const int col = colBase + waveN * 64 + nt * 16 + l16;
      const float bv = bias[col];
#pragma unroll
      for (int r = 0; r < 4; ++r)
        C[(size_t)(row + r) * 1024 + col] = acc[mt][nt][r] + bv;
    }
  }
}

// ---------------- paired flash attention (R15: K/V double-buffer prefetch) ----
__global__ __launch_bounds__(256) void attn_mfma(
    const __bf16* __restrict__ Qp, const __bf16* __restrict__ Kp,
    const __bf16* __restrict__ VT, __bf16* __restrict__ Aout) {
  __shared__ __bf16 sK[2][128 * 64];   // 32 KB, swizzled packed K lines
  __shared__ __bf16 sV[2][64 * 128];   // 32 KB, swizzled V^T
  __shared__ __bf16 sP[4 * 16 * 128];  // 16 KB, per-wave P regions

  const int tid = threadIdx.x;
  const int lane = tid & 63;
  const int wave = tid >> 6;
  const int quad = lane >> 4;
  const int l16 = lane & 15;
  const int swq = l16 & 7;

  const int bh = blockIdx.x >> 3;
  const int pr = blockIdx.x & 7;
  const int b = bh >> 4, h = bh & 15;
  const int qbA = pr * 64, qbB = (15 - pr) * 64;
  const int ktA_max = pr >> 1, ktB_max = (15 - pr) >> 1;

  const __bf16* Qb = Qp + ((size_t)bh << 16);
  const __bf16* Kb = Kp + ((size_t)bh << 16);
  const __bf16* VTb = VT + (size_t)bh * 64 * 1024;

  bf16x8 qA0A, qA1A, qA0B, qA1B;
  {
    const __bf16* qr = Qb + (size_t)(qbA + wave * 16 + l16) * 64 + quad * 8;
    qA0A = *(const bf16x8*)qr;
    qA1A = *(const bf16x8*)(qr + 32);
    qr = Qb + (size_t)(qbB + wave * 16 + l16) * 64 + quad * 8;
    qA0B = *(const bf16x8*)qr;
    qA1B = *(const bf16x8*)(qr + 32);
  }

  f32x4 OA[4] = {}, OB[4] = {};
  float psA[4] = {0.f, 0.f, 0.f, 0.f}, psB[4] = {0.f, 0.f, 0.f, 0.f};
  __bf16* pw = sP + wave * 2048;

#define ATTN_STAGE(bi, kbase)                                                  \
  _Pragma("unroll") for (int i_ = 0; i_ < 4; ++i_) {                           \
    const int rb = wave * 32 + i_ * 8;                                         \
    load_lds16(Kb + (size_t)((kbase) + rb + (lane >> 3)) * 64 +                \
                   (((lane & 7) ^ ((lane >> 3) & 7)) << 3),                    \
               &sK[bi][rb * 64]);                                              \
  }                                                                            \
  _Pragma("unroll") for (int i_ = 0; i_ < 4; ++i_) {                           \
    const int db = wave * 16 + i_ * 4;                                         \
    const int d = db + (lane >> 4);                                            \
    load_lds16(VTb + (size_t)d * 1024 + (kbase) +                              \
                   (((lane & 15) ^ (d & 7)) << 3),                             \
               &sV[bi][db * 128]);                                             \
  }

  // prologue: stage tile 0
  ATTN_STAGE(0, 0);
  asm volatile("s_waitcnt vmcnt(0)" ::: "memory");
  BAR8;

  for (int kt = 0; kt <= ktB_max; ++kt) {
    const int kb = kt * 128;
    const int cur = kt & 1;
    // issue next tile's loads first; they land under this iter's compute.
    // Buffer cur^1 was last read in iter kt-1, whose readers all passed the
    // end-of-(kt-1) barrier -> safe to overwrite.
    if (kt < ktB_max) { ATTN_STAGE(cur ^ 1, kb + 128); }
    const __bf16* skc = sK[cur];
    const __bf16* svc = sV[cur];

    // ================= q-tile B (always active) =================
    {
      float sc[8][4];
      __builtin_amdgcn_s_setprio(1);
#pragma unroll
      for (int n = 0; n < 8; ++n) {
        const int key = n * 16 + l16;
        bf16x8 kB0 = *(const bf16x8*)(&skc[key * 64 + ((quad ^ swq) << 3)]);
        bf16x8 kB1 = *(const bf16x8*)(&skc[key * 64 + (((quad + 4) ^ swq) << 3)]);
        f32x4 c = {};
        c = __builtin_amdgcn_mfma_f32_16x16x32_bf16(qA0B, kB0, c, 0, 0, 0);
        c = __builtin_amdgcn_mfma_f32_16x16x32_bf16(qA1B, kB1, c, 0, 0, 0);
#pragma unroll
        for (int r = 0; r < 4; ++r) sc[n][r] = c[r] * 0.125f;
      }
      __builtin_amdgcn_s_setprio(0);
      if (kt == ktB_max) {
#pragma unroll
        for (int n = 0; n < 8; ++n) {
          const int kg = kb + n * 16 + l16;
#pragma unroll
          for (int r = 0; r < 4; ++r)
            if (kg > qbB + wave * 16 + quad * 4 + r) sc[n][r] = -1.0e30f;
        }
      }
#pragma unroll
      for (int n = 0; n < 8; ++n)
#pragma unroll
        for (int r = 0; r < 4; ++r) {
          float p = __expf(fminf(sc[n][r], 60.0f));
          sc[n][r] = p;
          psB[r] += p;
        }
      {
        const int kb8 = l16 >> 3, lo = l16 & 7;
#pragma unroll
        for (int n = 0; n < 8; ++n) {
          const int chunk = n * 2 + kb8;
#pragma unroll
          for (int r = 0; r < 4; ++r) {
            const int q = quad * 4 + r;
            pw[q * 128 + ((chunk ^ (q & 7)) << 3) + lo] = (__bf16)sc[n][r];
          }
        }
      }
      __builtin_amdgcn_s_setprio(1);
#pragma unroll
      for (int cc = 0; cc < 4; ++cc) {
        bf16x8 pA = *(const bf16x8*)(&pw[l16 * 128 + (((cc * 4 + quad) ^ swq) << 3)]);
#pragma unroll
        for (int nt = 0; nt < 4; ++nt) {
          bf16x8 vB = *(const bf16x8*)(&svc[(nt * 16 + l16) * 128 +
                                            (((cc * 4 + quad) ^ swq) << 3)]);
          OB[nt] = __builtin_amdgcn_mfma_f32_16x16x32_bf16(pA, vB, OB[nt], 0, 0, 0);
        }
      }
      __builtin_amdgcn_s_setprio(0);
    }

    // ================= q-tile A (active while kt <= ktA_max) =================
    if (kt <= ktA_max) {
      float sc[8][4];
      __builtin_amdgcn_s_setprio(1);
#pragma unroll
      for (int n = 0; n < 8; ++n) {
        const int key = n * 16 + l16;
        bf16x8 kB0 = *(const bf16x8*)(&skc[key * 64 + ((quad ^ swq) << 3)]);
        bf16x8 kB1 = *(const bf16x8*)(&skc[key * 64 + (((quad + 4) ^ swq) << 3)]);
        f32x4 c = {};
        c = __builtin_amdgcn_mfma_f32_16x16x32_bf16(qA0A, kB0, c, 0, 0, 0);
        c = __builtin_amdgcn_mfma_f32_16x16x32_bf16(qA1A, kB1, c, 0, 0, 0);
#pragma unroll
        for (int r = 0; r < 4; ++r) sc[n][r] = c[r] * 0.125f;
      }
      __builtin_amdgcn_s_setprio(0);
      if (kt == ktA_max) {
#pragma unroll
        for (int n = 0; n < 8; ++n) {
          const int kg = kb + n * 16 + l16;
#pragma unroll
          for (int r = 0; r < 4; ++r)
            if (kg > qbA + wave * 16 + quad * 4 + r) sc[n][r] = -1.0e30f;
        }
      }
#pragma unroll
      for (int n = 0; n < 8; ++n)
#pragma unroll
        for (int r = 0; r < 4; ++r) {
          float p = __expf(fminf(sc[n][r], 60.0f));
          sc[n][r] = p;
          psA[r] += p;
        }
      {
        const int kb8 = l16 >> 3, lo = l16 & 7;
#pragma unroll
        for (int n = 0; n < 8; ++n) {
          const int chunk = n * 2 + kb8;
#pragma unroll
          for (int r = 0; r < 4; ++r) {
            const int q = quad * 4 + r;
            pw[q * 128 + ((chunk ^ (q & 7)) << 3) + lo] = (__bf16)sc[n][r];
          }
        }
      }
      __builtin_amdgcn_s_setprio(1);
#pragma unroll
      for (int cc = 0; cc < 4; ++cc) {
        bf16x8 pA = *(const bf16x8*)(&pw[l16 * 128 + (((cc * 4 + quad) ^ swq) << 3)]);
#pragma unroll
        for (int nt = 0; nt < 4; ++nt) {
          bf16x8 vB = *(const bf16x8*)(&svc[(nt * 16 + l16) * 128 +
                                            (((cc * 4 + quad) ^ swq) << 3)]);
          OA[nt] = __builtin_amdgcn_mfma_f32_16x16x32_bf16(pA, vB, OA[nt], 0, 0, 0);
        }
      }
      __builtin_amdgcn_s_setprio(0);
    }

    // next buffer fully staged (loads issued ~a full compute ago) + all waves
    // done reading the current buffer.
    if (kt < ktB_max) {
      asm volatile("s_waitcnt vmcnt(0)" ::: "memory");
      BAR8;
    }
  }

  // ---- epilogue
  float invA[4], invB[4];
#pragma unroll
  for (int r = 0; r < 4; ++r) {
    float pa = psA[r], pb = psB[r];
    pa += __shfl_xor(pa, 1); pb += __shfl_xor(pb, 1);
    pa += __shfl_xor(pa, 2); pb += __shfl_xor(pb, 2);
    pa += __shfl_xor(pa, 4); pb += __shfl_xor(pb, 4);
    pa += __shfl_xor(pa, 8); pb += __shfl_xor(pb, 8);
    invA[r] = 1.0f / pa;
    invB[r] = 1.0f / pb;
  }
#pragma unroll
  for (int nt = 0; nt < 4; ++nt) {
#pragma unroll
    for (int r = 0; r < 4; ++r) {
      const int qA = qbA + wave * 16 + quad * 4 + r;
      const int qB = qbB + wave * 16 + quad * 4 + r;
      Aout[((size_t)b * 1024 + qA) * 1024 + h * 64 + nt * 16 + l16] =
          (__bf16)(OA[nt][r] * invA[r]);
      Aout[((size_t)b * 1024 + qB) * 1024 + h * 64 + nt * 16 + l16] =
          (__bf16)(OB[nt][r] * invB[r]);
    }
  }
}

// ---------------- launch ----------------
extern "C" void kernel_launch(void* const* d_in, const int* in_sizes, int n_in,
                              void* d_out, int out_size, void* d_ws,
                              size_t ws_size, hipStream_t stream) {
  const float* x      = (const float*)d_in[0];
  const float* w_attn = (const float*)d_in[1];
  const float* b_attn = (const float*)d_in[2];
  const float* w_proj = (const float*)d_in[3];
  const float* b_proj = (const float*)d_in[4];
  float* out = (float*)d_out;

  char* ws = (char*)d_ws;
  __bf16* WT_attn = (__bf16*)(ws);                  //  6 MB
  __bf16* WT_proj = (__bf16*)(ws + 6291456);        //  2 MB
  __bf16* Xb      = (__bf16*)(ws + 8388608);        //  8 MB
  __bf16* Qp      = (__bf16*)(ws + 16777216);       //  8 MB [bh][s][64]
  __bf16* Kp      = (__bf16*)(ws + 25165824);       //  8 MB [bh][s][64]
  __bf16* VT      = (__bf16*)(ws + 33554432);       //  8 MB [bh][d][s]
  __bf16* Aattn   = (__bf16*)(ws + 41943040);       //  8 MB (end 50 MB)

  prep<<<5120, 256, 0, stream>>>(x, w_attn, w_proj, Xb, WT_attn, WT_proj);
  gemm_qkv8<<<192, 512, 0, stream>>>(Xb, WT_attn, b_attn, Qp, Kp, VT);
  attn_mfma<<<512, 256, 0, stream>>>(Qp, Kp, VT, Aattn);
  gemm_out<<<dim3(8, 32), 256, 0, stream>>>(Aattn, WT_proj, b_proj, out);
}

// Round 4
// 164.862 us; speedup vs baseline: 1.0936x; 1.0364x over previous
//
#include <hip/hip_runtime.h>
#include <hip/hip_bf16.h>

// GPT-2 attention block. Inputs/outputs fp32; internal bf16 MFMA, fp32 accum.
// B=4, S=1024, D=1024, H=16, hd=64.
//
// R16: LOCALITY round (index-only changes).
//  - attn_mfma: block remap bh=blk&63, pr=blk>>6 -> all 8 pr-siblings of one
//    bh land on XCD bh%8; K/V (256 KB/bh) become L2-resident instead of being
//    fetched by 8 XCDs (~106 MB -> ~24 MB).
//  - gemm_out: grid dim3(32,8) with row on x -> XCD = rowTile%8; A-panels L2
//    resident (fetch 66 -> 24 MB).
//  - gemm_qkv8: 4x3 2D XCD tile chunks (working set 7 -> 5 MB/XCD).
//  Everything else verbatim from R15.

typedef __bf16 bf16x8 __attribute__((ext_vector_type(8)));
typedef __bf16 bf16x4 __attribute__((ext_vector_type(4)));
typedef float f32x4 __attribute__((ext_vector_type(4)));

__device__ __forceinline__ void load_lds16(const void* g, void* l) {
  __builtin_amdgcn_global_load_lds(
      (const __attribute__((address_space(1))) void*)g,
      (__attribute__((address_space(3))) void*)l, 16, 0, 0);
}

#define BAR8 asm volatile("s_barrier" ::: "memory")
#define LGKM0 asm volatile("s_waitcnt lgkmcnt(0)" ::: "memory")

// ---------------- fused prep: transpose w_attn, w_proj; convert x ----------------
__global__ __launch_bounds__(256) void prep(
    const float* __restrict__ x, const float* __restrict__ w_attn,
    const float* __restrict__ w_proj, __bf16* __restrict__ Xb,
    __bf16* __restrict__ WT_attn, __bf16* __restrict__ WT_proj) {
  __shared__ __bf16 tile[32][33];
  const int blk = blockIdx.x;
  const int tid = threadIdx.x;
  if (blk < 4096) {  // transpose (block-uniform branch)
    const float* W;
    __bf16* WT;
    int n0, k0, N;
    if (blk < 3072) {
      W = w_attn; WT = WT_attn; N = 3072;
      n0 = (blk % 96) * 32; k0 = (blk / 96) * 32;
    } else {
      W = w_proj; WT = WT_proj; N = 1024;
      const int t = blk - 3072;
      n0 = (t & 31) * 32; k0 = (t >> 5) * 32;
    }
    const int tx = tid & 31, ty = tid >> 5;
#pragma unroll
    for (int j = 0; j < 32; j += 8)
      tile[ty + j][tx] = (__bf16)W[(size_t)(k0 + ty + j) * N + n0 + tx];
    __syncthreads();
#pragma unroll
    for (int j = 0; j < 32; j += 8)
      WT[(size_t)(n0 + ty + j) * 1024 + k0 + tx] = tile[tx][ty + j];
  } else {  // x -> bf16, 16 elems/thread
    const size_t i = (size_t)(blk - 4096) * 4096 + tid * 16;
    const float4* xp = (const float4*)(x + i);
    float4 a = xp[0], b = xp[1], c = xp[2], d = xp[3];
    bf16x8 o0, o1;
    o0[0] = (__bf16)a.x; o0[1] = (__bf16)a.y; o0[2] = (__bf16)a.z; o0[3] = (__bf16)a.w;
    o0[4] = (__bf16)b.x; o0[5] = (__bf16)b.y; o0[6] = (__bf16)b.z; o0[7] = (__bf16)b.w;
    o1[0] = (__bf16)c.x; o1[1] = (__bf16)c.y; o1[2] = (__bf16)c.z; o1[3] = (__bf16)c.w;
    o1[4] = (__bf16)d.x; o1[5] = (__bf16)d.y; o1[6] = (__bf16)d.z; o1[7] = (__bf16)d.w;
    *(bf16x8*)(Xb + i) = o0;
    *(bf16x8*)(Xb + i + 8) = o1;
  }
}

// ================= GEMM1: 256x256 8-phase template (QKV) =================
// 512 threads = 8 waves (2M x 4N). BK=64, double-buffered 128 KB LDS.
// LDS map (bf16 elems): buf b at b*32768; A halves at +0,+8192; B at +16384,+24576.
// Swizzle: slot s of row r holds k-chunk c = s ^ (r&7) (16B chunks).
// Stage schedule per iter t (tiles E=2t in buf0, O=2t+1 in buf1):
//   ph1: O.A1 | ph3: (E+2).B0 | ph4: (E+2).B1,(E+2).A0 + vmcnt(6)
//   ph5: (E+2).A1 | ph7: (O+2).B0 | ph8: (O+2).B1,(O+2).A0 + vmcnt(6)
// Epilogue: seg 0/1 -> packed Qp/Kp. seg 2 -> VT[bh][d][s] directly via LDS
// transpose (smem8 reused; element [c][r] stored at c*256 + (r ^ ((c&15)<<4))).

#define STG(GMAT, GROW0, K0, LOFF)                                             \
  _Pragma("unroll") for (int i_ = 0; i_ < 2; ++i_)                             \
    load_lds16((GMAT) + (size_t)((GROW0) + i_ * 64 + wave * 8 + srow) * 1024 + \
                   (K0) + schunk * 8,                                          \
               smem8 + (LOFF) + (i_ * 64 + wave * 8) * 64);

#define LDA8(BASE, MH)                                                         \
  _Pragma("unroll") for (int m_ = 0; m_ < 4; ++m_)                             \
  _Pragma("unroll") for (int kk_ = 0; kk_ < 2; ++kk_)                          \
    af[m_][kk_] = *(const bf16x8*)((BASE) + ((MH)*64 + m_ * 16 + l16) * 64 +   \
                                   (((kk_ * 4 + quad) ^ rsw) * 8));

#define LDB8(BASE, NLO)                                                        \
  _Pragma("unroll") for (int n_ = 0; n_ < 2; ++n_)                             \
  _Pragma("unroll") for (int kk_ = 0; kk_ < 2; ++kk_)                          \
    bf[(NLO) + n_][kk_] =                                                      \
        *(const bf16x8*)((BASE) + ((waveN & 1) * 64 + ((NLO) + n_) * 16 +      \
                                   l16) * 64 +                                 \
                         (((kk_ * 4 + quad) ^ rsw) * 8));

#define MFMA_HALF(MH, NLO)                                                     \
  __builtin_amdgcn_s_setprio(1);                                               \
  _Pragma("unroll") for (int m_ = 0; m_ < 4; ++m_)                             \
  _Pragma("unroll") for (int n_ = 0; n_ < 2; ++n_) {                           \
    acc[(MH)*4 + m_][(NLO) + n_] = __builtin_amdgcn_mfma_f32_16x16x32_bf16(    \
        af[m_][0], bf[(NLO) + n_][0], acc[(MH)*4 + m_][(NLO) + n_], 0, 0, 0);  \
    acc[(MH)*4 + m_][(NLO) + n_] = __builtin_amdgcn_mfma_f32_16x16x32_bf16(    \
        af[m_][1], bf[(NLO) + n_][1], acc[(MH)*4 + m_][(NLO) + n_], 0, 0, 0);  \
  }                                                                            \
  __builtin_amdgcn_s_setprio(0);

__global__ __launch_bounds__(512, 2) void gemm_qkv8(
    const __bf16* __restrict__ A, const __bf16* __restrict__ BT,
    const float* __restrict__ bias, __bf16* __restrict__ Qp,
    __bf16* __restrict__ Kp, __bf16* __restrict__ Vt) {
  __shared__ __bf16 smem8[65536];  // 128 KB
  const int tid = threadIdx.x;
  const int lane = tid & 63;
  const int wave = tid >> 6;
  const int waveM = wave >> 2;  // 0..1
  const int waveN = wave & 3;   // 0..3
  const int l16 = lane & 15;
  const int quad = lane >> 4;
  const int rsw = l16 & 7;
  const int srow = lane >> 3;            // staging row-in-8
  const int schunk = (lane & 7) ^ srow;  // pre-swizzled source chunk

  // XCD-aware 2D chunking: XCD c gets a 4(tm) x 6(tn) block of the 16x12 grid
  // -> per-XCD working set A 2MB + B 3MB = 5MB (was 7MB row-chunked).
  const int bid = blockIdx.x;
  const int c = bid & 7, l = bid >> 3;
  const int tm = (c >> 1) * 4 + l / 6;
  const int tn = (c & 1) * 6 + l % 6;
  const int rowBase = tm * 256;
  const int colBase = tn * 256;

  const __bf16* aRd = smem8 + waveM * 8192;                 // buf0 A (own half)
  const __bf16* bRd = smem8 + 16384 + (waveN >> 1) * 8192;  // buf0 B (own half)

  f32x4 acc[8][4] = {};
  bf16x8 af[4][2], bf[4][2];

  // ---- prologue: stage T0 fully, T1 {B0,B1,A0}
  STG(A, rowBase, 0, 0);
  STG(A, rowBase + 128, 0, 8192);
  STG(BT, colBase, 0, 16384);
  STG(BT, colBase + 128, 0, 24576);
  STG(BT, colBase, 64, 32768 + 16384);
  STG(BT, colBase + 128, 64, 32768 + 24576);
  STG(A, rowBase, 64, 32768);
  asm volatile("s_waitcnt vmcnt(6)" ::: "memory");  // T0 landed
  BAR8;

  for (int t = 0; t < 8; ++t) {
    const int kO = t * 128 + 64;   // odd tile K offset (for O.A1 stage)
    const int kS2 = t * 128 + 128; // prefetch tile for buf0
    const int kS3 = t * 128 + 192; // prefetch tile for buf1
    const bool s2 = kS2 < 1024;
    const bool s3 = kS3 < 1024;

    // ---- phase 1: read E.A-mh0 + E.B-n01 ; stage O.A1
    LDA8(aRd, 0);
    LDB8(bRd, 0);
    STG(A, rowBase + 128, kO, 32768 + 8192);
    BAR8; LGKM0;
    MFMA_HALF(0, 0);
    BAR8;

    // ---- phase 2: read E.B-n23
    LDB8(bRd, 2);
    BAR8; LGKM0;
    MFMA_HALF(0, 2);
    BAR8;

    // ---- phase 3: read E.A-mh1 ; stage (E+2).B0
    LDA8(aRd, 1);
    if (s2) { STG(BT, colBase, kS2, 16384); }
    BAR8; LGKM0;
    MFMA_HALF(1, 2);
    BAR8;

    // ---- phase 4: stage (E+2).B1 + (E+2).A0 ; counted vmcnt
    if (s2) {
      STG(BT, colBase + 128, kS2, 24576);
      STG(A, rowBase, kS2, 0);
      asm volatile("s_waitcnt vmcnt(6)" ::: "memory");  // all of O landed
    } else {
      asm volatile("s_waitcnt vmcnt(0)" ::: "memory");  // last iter: drain
    }
    BAR8;
    MFMA_HALF(1, 0);
    BAR8;

    // ---- phase 5: read O.A-mh0 + O.B-n01 ; stage (E+2).A1
    LDA8(aRd + 32768, 0);
    LDB8(bRd + 32768, 0);
    if (s2) { STG(A, rowBase + 128, kS2, 8192); }
    BAR8; LGKM0;
    MFMA_HALF(0, 0);
    BAR8;

    // ---- phase 6: read O.B-n23
    LDB8(bRd + 32768, 2);
    BAR8; LGKM0;
    MFMA_HALF(0, 2);
    BAR8;

    // ---- phase 7: read O.A-mh1 ; stage (O+2).B0
    LDA8(aRd + 32768, 1);
    if (s3) { STG(BT, colBase, kS3, 32768 + 16384); }
    BAR8; LGKM0;
    MFMA_HALF(1, 2);
    BAR8;

    // ---- phase 8: stage (O+2).B1 + (O+2).A0 ; counted vmcnt
    if (s3) {
      STG(BT, colBase + 128, kS3, 32768 + 24576);
      STG(A, rowBase, kS3, 32768);
    }
    asm volatile("s_waitcnt vmcnt(6)" ::: "memory");  // all of E+2 landed
    BAR8;
    MFMA_HALF(1, 0);
    BAR8;
  }

  const int seg = colBase >> 10;  // 0=Q 1=K 2=V (block-uniform)
  if (seg == 2) {
    // ---- V epilogue: transpose 256x256 tile in LDS, write VT[bh][d][s].
    // smem8 is dead here (phase-4 t=7 did vmcnt(0); final BAR8 passed).
#pragma unroll
    for (int mm = 0; mm < 8; ++mm) {
      const int r0 = waveM * 128 + mm * 16 + quad * 4;
#pragma unroll
      for (int n = 0; n < 4; ++n) {
        const int cR = waveN * 64 + n * 16 + l16;
        const float bv = bias[colBase + cR];
        bf16x4 pk;
#pragma unroll
        for (int r = 0; r < 4; ++r) pk[r] = (__bf16)(acc[mm][n][r] + bv);
        *(bf16x4*)(&smem8[cR * 256 + (r0 ^ (l16 << 4))]) = pk;
      }
    }
    __syncthreads();
    const int b_ = rowBase >> 10;
    const int s0 = rowBase & 1023;
    const int hBase = (colBase & 1023) >> 6;
    const int ch = lane & 31;
#pragma unroll
    for (int p = 0; p < 16; ++p) {
      const int c2 = p * 16 + wave * 2 + (lane >> 5);
      bf16x8 v =
          *(const bf16x8*)(&smem8[c2 * 256 + ((ch * 8) ^ ((c2 & 15) << 4))]);
      const int bhd = (b_ * 16 + hBase + (c2 >> 6)) * 64 + (c2 & 63);
      *(bf16x8*)(&Vt[(size_t)bhd * 1024 + s0 + ch * 8]) = v;
    }
  } else {
    // ---- Q/K epilogue: packed [bh][s][64]
#pragma unroll
    for (int mm = 0; mm < 8; ++mm) {
      const int row0 = rowBase + waveM * 128 + mm * 16 + quad * 4;
#pragma unroll
      for (int n = 0; n < 4; ++n) {
        const int col = colBase + waveN * 64 + n * 16 + l16;
        const float bv = bias[col];
        const int cc = col & 1023;
        __bf16* dst = (seg == 0) ? Qp : Kp;
#pragma unroll
        for (int r = 0; r < 4; ++r) {
          const int row = row0 + r;
          const float v = acc[mm][n][r] + bv;
          const int bh = ((row >> 10) << 4) + (cc >> 6);
          dst[((size_t)bh << 16) + (size_t)(row & 1023) * 64 + (cc & 63)] =
              (__bf16)v;
        }
      }
    }
  }
}

// ---------------- GEMM2: out = A @ WT^T + bias, depth-2 pipelined ----------------
// Grid dim3(32,8): row tile on x -> XCD = rowTile%8 -> A-panels L2-resident.
__global__ __launch_bounds__(256) void gemm_out(
    const __bf16* __restrict__ A, const __bf16* __restrict__ BT,
    const float* __restrict__ bias, float* __restrict__ C) {
  __shared__ __bf16 sA[3][128 * 32];  // 24 KB
  __shared__ __bf16 sB[3][128 * 32];  // 24 KB
  const int tid = threadIdx.x;
  const int lane = tid & 63;
  const int wave = tid >> 6;
  const int waveM = wave >> 1, waveN = wave & 1;
  const int quad = lane >> 4;
  const int l16 = lane & 15;
  const int rowBase = blockIdx.x * 128;
  const int colBase = blockIdx.y * 128;
  const int rIn = lane >> 2;
  const int sIn = lane & 3;
  const int gc = sIn ^ (rIn & 3) ^ ((rIn >> 2) & 3);
  const int readSlot = quad ^ (l16 & 3) ^ ((l16 >> 2) & 3);
  f32x4 acc[4][4] = {};

#define GO_STAGE(bi, k0_)                                                      \
  _Pragma("unroll") for (int j_ = 0; j_ < 2; ++j_) {                           \
    const int rb = wave * 32 + j_ * 16;                                        \
    load_lds16(&A[(size_t)(rowBase + rb + rIn) * 1024 + (k0_) + gc * 8],       \
               &sA[bi][rb * 32]);                                              \
    load_lds16(&BT[(size_t)(colBase + rb + rIn) * 1024 + (k0_) + gc * 8],      \
               &sB[bi][rb * 32]);                                              \
  }

  // prologue: tiles 0 and 1 in flight (4 loads each per wave)
  GO_STAGE(0, 0);
  GO_STAGE(1, 32);
  asm volatile("s_waitcnt vmcnt(4)" ::: "memory");  // tile 0 landed
  BAR8;

#pragma unroll
  for (int i = 0; i < 32; ++i) {
    if (i + 2 < 32) { GO_STAGE((i + 2) % 3, (i + 2) * 32); }
    const __bf16* sAc = sA[i % 3];
    const __bf16* sBc = sB[i % 3];
    bf16x8 af[4], bfr[4];
#pragma unroll
    for (int mt = 0; mt < 4; ++mt)
      af[mt] = *(const bf16x8*)(&sAc[(waveM * 64 + mt * 16 + l16) * 32 +
                                     readSlot * 8]);
#pragma unroll
    for (int nt = 0; nt < 4; ++nt)
      bfr[nt] = *(const bf16x8*)(&sBc[(waveN * 64 + nt * 16 + l16) * 32 +
                                      readSlot * 8]);
    __builtin_amdgcn_s_setprio(1);
#pragma unroll
    for (int mt = 0; mt < 4; ++mt)
#pragma unroll
      for (int nt = 0; nt < 4; ++nt)
        acc[mt][nt] = __builtin_amdgcn_mfma_f32_16x16x32_bf16(
            af[mt], bfr[nt], acc[mt][nt], 0, 0, 0);
    __builtin_amdgcn_s_setprio(0);
    if (i + 1 < 32) {
      if (i + 2 < 32) {
        asm volatile("s_waitcnt vmcnt(4)" ::: "memory");  // tile i+1 landed
      } else {
        asm volatile("s_waitcnt vmcnt(0)" ::: "memory");  // drain last stage
      }
      BAR8;
    }
  }

#pragma unroll
  for (int mt = 0; mt < 4; ++mt) {
    const int row = rowBase + waveM * 64 + mt * 16 + quad * 4;
#pragma unroll
    for (int nt = 0; nt < 4; ++nt) {
      const int col = colBase + waveN * 64 + nt * 16 + l16;
      const float bv = bias[col];
#pragma unroll
      for (int r = 0; r < 4; ++r)
        C[(size_t)(row + r) * 1024 + col] = acc[mt][nt][r] + bv;
    }
  }
}

// ---------------- paired flash attention (R16: bh-major XCD mapping) ----------
__global__ __launch_bounds__(256) void attn_mfma(
    const __bf16* __restrict__ Qp, const __bf16* __restrict__ Kp,
    const __bf16* __restrict__ VT, __bf16* __restrict__ Aout) {
  __shared__ __bf16 sK[2][128 * 64];   // 32 KB, swizzled packed K lines
  __shared__ __bf16 sV[2][64 * 128];   // 32 KB, swizzled V^T
  __shared__ __bf16 sP[4 * 16 * 128];  // 16 KB, per-wave P regions

  const int tid = threadIdx.x;
  const int lane = tid & 63;
  const int wave = tid >> 6;
  const int quad = lane >> 4;
  const int l16 = lane & 15;
  const int swq = l16 & 7;

  // bh in low bits -> XCD = bh%8: all 8 pr-siblings of a bh share one XCD,
  // so its K/V (256 KB) is fetched into that XCD's L2 once.
  const int bh = blockIdx.x & 63;
  const int pr = blockIdx.x >> 6;
  const int b = bh >> 4, h = bh & 15;
  const int qbA = pr * 64, qbB = (15 - pr) * 64;
  const int ktA_max = pr >> 1, ktB_max = (15 - pr) >> 1;

  const __bf16* Qb = Qp + ((size_t)bh << 16);
  const __bf16* Kb = Kp + ((size_t)bh << 16);
  const __bf16* VTb = VT + (size_t)bh * 64 * 1024;

  bf16x8 qA0A, qA1A, qA0B, qA1B;
  {
    const __bf16* qr = Qb + (size_t)(qbA + wave * 16 + l16) * 64 + quad * 8;
    qA0A = *(const bf16x8*)qr;
    qA1A = *(const bf16x8*)(qr + 32);
    qr = Qb + (size_t)(qbB + wave * 16 + l16) * 64 + quad * 8;
    qA0B = *(const bf16x8*)qr;
    qA1B = *(const bf16x8*)(qr + 32);
  }

  f32x4 OA[4] = {}, OB[4] = {};
  float psA[4] = {0.f, 0.f, 0.f, 0.f}, psB[4] = {0.f, 0.f, 0.f, 0.f};
  __bf16* pw = sP + wave * 2048;

#define ATTN_STAGE(bi, kbase)                                                  \
  _Pragma("unroll") for (int i_ = 0; i_ < 4; ++i_) {                           \
    const int rb = wave * 32 + i_ * 8;                                         \
    load_lds16(Kb + (size_t)((kbase) + rb + (lane >> 3)) * 64 +                \
                   (((lane & 7) ^ ((lane >> 3) & 7)) << 3),                    \
               &sK[bi][rb * 64]);                                              \
  }                                                                            \
  _Pragma("unroll") for (int i_ = 0; i_ < 4; ++i_) {                           \
    const int db = wave * 16 + i_ * 4;                                         \
    const int d = db + (lane >> 4);                                            \
    load_lds16(VTb + (size_t)d * 1024 + (kbase) +                              \
                   (((lane & 15) ^ (d & 7)) << 3),                             \
               &sV[bi][db * 128]);                                             \
  }

  // prologue: stage tile 0
  ATTN_STAGE(0, 0);
  asm volatile("s_waitcnt vmcnt(0)" ::: "memory");
  BAR8;

  for (int kt = 0; kt <= ktB_max; ++kt) {
    const int kb = kt * 128;
    const int cur = kt & 1;
    // issue next tile's loads first; they land under this iter's compute.
    if (kt < ktB_max) { ATTN_STAGE(cur ^ 1, kb + 128); }
    const __bf16* skc = sK[cur];
    const __bf16* svc = sV[cur];

    // ================= q-tile B (always active) =================
    {
      float sc[8][4];
      __builtin_amdgcn_s_setprio(1);
#pragma unroll
      for (int n = 0; n < 8; ++n) {
        const int key = n * 16 + l16;
        bf16x8 kB0 = *(const bf16x8*)(&skc[key * 64 + ((quad ^ swq) << 3)]);
        bf16x8 kB1 = *(const bf16x8*)(&skc[key * 64 + (((quad + 4) ^ swq) << 3)]);
        f32x4 c = {};
        c = __builtin_amdgcn_mfma_f32_16x16x32_bf16(qA0B, kB0, c, 0, 0, 0);
        c = __builtin_amdgcn_mfma_f32_16x16x32_bf16(qA1B, kB1, c, 0, 0, 0);
#pragma unroll
        for (int r = 0; r < 4; ++r) sc[n][r] = c[r] * 0.125f;
      }
      __builtin_amdgcn_s_setprio(0);
      if (kt == ktB_max) {
#pragma unroll
        for (int n = 0; n < 8; ++n) {
          const int kg = kb + n * 16 + l16;
#pragma unroll
          for (int r = 0; r < 4; ++r)
            if (kg > qbB + wave * 16 + quad * 4 + r) sc[n][r] = -1.0e30f;
        }
      }
#pragma unroll
      for (int n = 0; n < 8; ++n)
#pragma unroll
        for (int r = 0; r < 4; ++r) {
          float p = __expf(fminf(sc[n][r], 60.0f));
          sc[n][r] = p;
          psB[r] += p;
        }
      {
        const int kb8 = l16 >> 3, lo = l16 & 7;
#pragma unroll
        for (int n = 0; n < 8; ++n) {
          const int chunk = n * 2 + kb8;
#pragma unroll
          for (int r = 0; r < 4; ++r) {
            const int q = quad * 4 + r;
            pw[q * 128 + ((chunk ^ (q & 7)) << 3) + lo] = (__bf16)sc[n][r];
          }
        }
      }
      __builtin_amdgcn_s_setprio(1);
#pragma unroll
      for (int cc = 0; cc < 4; ++cc) {
        bf16x8 pA = *(const bf16x8*)(&pw[l16 * 128 + (((cc * 4 + quad) ^ swq) << 3)]);
#pragma unroll
        for (int nt = 0; nt < 4; ++nt) {
          bf16x8 vB = *(const bf16x8*)(&svc[(nt * 16 + l16) * 128 +
                                            (((cc * 4 + quad) ^ swq) << 3)]);
          OB[nt] = __builtin_amdgcn_mfma_f32_16x16x32_bf16(pA, vB, OB[nt], 0, 0, 0);
        }
      }
      __builtin_amdgcn_s_setprio(0);
    }

    // ================= q-tile A (active while kt <= ktA_max) =================
    if (kt <= ktA_max) {
      float sc[8][4];
      __builtin_amdgcn_s_setprio(1);
#pragma unroll
      for (int n = 0; n < 8; ++n) {
        const int key = n * 16 + l16;
        bf16x8 kB0 = *(const bf16x8*)(&skc[key * 64 + ((quad ^ swq) << 3)]);
        bf16x8 kB1 = *(const bf16x8*)(&skc[key * 64 + (((quad + 4) ^ swq) << 3)]);
        f32x4 c = {};
        c = __builtin_amdgcn_mfma_f32_16x16x32_bf16(qA0A, kB0, c, 0, 0, 0);
        c = __builtin_amdgcn_mfma_f32_16x16x32_bf16(qA1A, kB1, c, 0, 0, 0);
#pragma unroll
        for (int r = 0; r < 4; ++r) sc[n][r] = c[r] * 0.125f;
      }
      __builtin_amdgcn_s_setprio(0);
      if (kt == ktA_max) {
#pragma unroll
        for (int n = 0; n < 8; ++n) {
          const int kg = kb + n * 16 + l16;
#pragma unroll
          for (int r = 0; r < 4; ++r)
            if (kg > qbA + wave * 16 + quad * 4 + r) sc[n][r] = -1.0e30f;
        }
      }
#pragma unroll
      for (int n = 0; n < 8; ++n)
#pragma unroll
        for (int r = 0; r < 4; ++r) {
          float p = __expf(fminf(sc[n][r], 60.0f));
          sc[n][r] = p;
          psA[r] += p;
        }
      {
        const int kb8 = l16 >> 3, lo = l16 & 7;
#pragma unroll
        for (int n = 0; n < 8; ++n) {
          const int chunk = n * 2 + kb8;
#pragma unroll
          for (int r = 0; r < 4; ++r) {
            const int q = quad * 4 + r;
            pw[q * 128 + ((chunk ^ (q & 7)) << 3) + lo] = (__bf16)sc[n][r];
          }
        }
      }
      __builtin_amdgcn_s_setprio(1);
#pragma unroll
      for (int cc = 0; cc < 4; ++cc) {
        bf16x8 pA = *(const bf16x8*)(&pw[l16 * 128 + (((cc * 4 + quad) ^ swq) << 3)]);
#pragma unroll
        for (int nt = 0; nt < 4; ++nt) {
          bf16x8 vB = *(const bf16x8*)(&svc[(nt * 16 + l16) * 128 +
                                            (((cc * 4 + quad) ^ swq) << 3)]);
          OA[nt] = __builtin_amdgcn_mfma_f32_16x16x32_bf16(pA, vB, OA[nt], 0, 0, 0);
        }
      }
      __builtin_amdgcn_s_setprio(0);
    }

    if (kt < ktB_max) {
      asm volatile("s_waitcnt vmcnt(0)" ::: "memory");
      BAR8;
    }
  }

  // ---- epilogue
  float invA[4], invB[4];
#pragma unroll
  for (int r = 0; r < 4; ++r) {
    float pa = psA[r], pb = psB[r];
    pa += __shfl_xor(pa, 1); pb += __shfl_xor(pb, 1);
    pa += __shfl_xor(pa, 2); pb += __shfl_xor(pb, 2);
    pa += __shfl_xor(pa, 4); pb += __shfl_xor(pb, 4);
    pa += __shfl_xor(pa, 8); pb += __shfl_xor(pb, 8);
    invA[r] = 1.0f / pa;
    invB[r] = 1.0f / pb;
  }
#pragma unroll
  for (int nt = 0; nt < 4; ++nt) {
#pragma unroll
    for (int r = 0; r < 4; ++r) {
      const int qA = qbA + wave * 16 + quad * 4 + r;
      const int qB = qbB + wave * 16 + quad * 4 + r;
      Aout[((size_t)b * 1024 + qA) * 1024 + h * 64 + nt * 16 + l16] =
          (__bf16)(OA[nt][r] * invA[r]);
      Aout[((size_t)b * 1024 + qB) * 1024 + h * 64 + nt * 16 + l16] =
          (__bf16)(OB[nt][r] * invB[r]);
    }
  }
}

// ---------------- launch ----------------
extern "C" void kernel_launch(void* const* d_in, const int* in_sizes, int n_in,
                              void* d_out, int out_size, void* d_ws,
                              size_t ws_size, hipStream_t stream) {
  const float* x      = (const float*)d_in[0];
  const float* w_attn = (const float*)d_in[1];
  const float* b_attn = (const float*)d_in[2];
  const float* w_proj = (const float*)d_in[3];
  const float* b_proj = (const float*)d_in[4];
  float* out = (float*)d_out;

  char* ws = (char*)d_ws;
  __bf16* WT_attn = (__bf16*)(ws);                  //  6 MB
  __bf16* WT_proj = (__bf16*)(ws + 6291456);        //  2 MB
  __bf16* Xb      = (__bf16*)(ws + 8388608);        //  8 MB
  __bf16* Qp      = (__bf16*)(ws + 16777216);       //  8 MB [bh][s][64]
  __bf16* Kp      = (__bf16*)(ws + 25165824);       //  8 MB [bh][s][64]
  __bf16* VT      = (__bf16*)(ws + 33554432);       //  8 MB [bh][d][s]
  __bf16* Aattn   = (__bf16*)(ws + 41943040);       //  8 MB (end 50 MB)

  prep<<<5120, 256, 0, stream>>>(x, w_attn, w_proj, Xb, WT_attn, WT_proj);
  gemm_qkv8<<<192, 512, 0, stream>>>(Xb, WT_attn, b_attn, Qp, Kp, VT);
  attn_mfma<<<512, 256, 0, stream>>>(Qp, Kp, VT, Aattn);
  gemm_out<<<dim3(32, 8), 256, 0, stream>>>(Aattn, WT_proj, b_proj, out);
}